// Round 4
// baseline (701.628 us; speedup 1.0000x reference)
//
#include <hip/hip_runtime.h>
#include <cstdint>
#include <cmath>

#define HWSZ    15000      // H*W = 100*150
#define W_FEAT  150
#define A_NUM   9
#define NPER    135000     // A_NUM * HWSZ
#define B_NUM   16
#define PRE_NMS 6000
#define POST_NMS 300
#define NBINS   16384      // top-14-bit histogram
#define CAND_CAP 8192
#define NMSB    512        // NMS chunk / block size (8 waves)

// 9 base anchors from generate_anchors(16,[0.5,1,2],[8,16,32]).
// ws=[23,16,11], hs=round(ws*ratios)=round([11.5,16,22])=[12,16,22]  (half-even)
__device__ __constant__ float ANC[9][4] = {
    {-84.f,  -40.f,  99.f,  55.f},
    {-176.f, -88.f, 191.f, 103.f},
    {-360.f,-184.f, 375.f, 199.f},
    {-56.f,  -56.f,  71.f,  71.f},
    {-120.f,-120.f, 135.f, 135.f},
    {-248.f,-248.f, 263.f, 263.f},
    {-36.f,  -80.f,  51.f,  95.f},
    {-80.f, -168.f,  95.f, 183.f},
    {-168.f,-344.f, 183.f, 359.f}};

__device__ __forceinline__ uint32_t fkey(float s) {
    uint32_t u = __float_as_uint(s);
    return (u & 0x80000000u) ? ~u : (u | 0x80000000u);  // monotone key
}

__device__ __forceinline__ bool iou_gt(const float4& q, float qa,
                                       const float4& c, float ca) {
    float xx1 = fmaxf(q.x, c.x);
    float yy1 = fmaxf(q.y, c.y);
    float xx2 = fminf(q.z, c.z);
    float yy2 = fminf(q.w, c.w);
    float iw = fmaxf(0.0f, __fadd_rn(__fsub_rn(xx2, xx1), 1.0f));
    float ih = fmaxf(0.0f, __fadd_rn(__fsub_rn(yy2, yy1), 1.0f));
    float inter = __fmul_rn(iw, ih);
    float den = __fsub_rn(__fadd_rn(qa, ca), inter);
    return __fdiv_rn(inter, den) > 0.7f;
}

__device__ __forceinline__ float area_of(const float4& c) {
    return __fmul_rn(__fadd_rn(__fsub_rn(c.z, c.x), 1.0f),
                     __fadd_rn(__fsub_rn(c.w, c.y), 1.0f));
}

// ---- K1: per-batch histogram of top-14 bits of score key --------------------
__global__ void k_hist(const float* __restrict__ scores, uint32_t* __restrict__ hist) {
    int b = blockIdx.y;
    int r = blockIdx.x * blockDim.x + threadIdx.x;
    if (r >= NPER) return;
    int a = r / HWSZ;
    int p = r - a * HWSZ;
    float s = scores[(size_t)(b * 18 + 9 + a) * HWSZ + p];
    atomicAdd(&hist[b * NBINS + (fkey(s) >> 18)], 1u);
}

// ---- K2: threshold bin via single-pass suffix scan (1024 thr) ---------------
__global__ __launch_bounds__(1024) void k_scan(const uint32_t* __restrict__ hist,
                                               uint32_t* __restrict__ thr) {
    int b = blockIdx.x, tid = threadIdx.x;
    __shared__ uint32_t psum[1024];
    int base = NBINS - 16 * (tid + 1);
    uint32_t s = 0;
    for (int i = 0; i < 16; ++i) s += hist[b * NBINS + base + i];
    psum[tid] = s;
    __syncthreads();
    for (int off = 1; off < 1024; off <<= 1) {   // cum-from-top over chunks
        uint32_t v = (tid >= off) ? psum[tid - off] : 0u;
        __syncthreads();
        psum[tid] += v;
        __syncthreads();
    }
    uint32_t above = (tid == 0) ? 0u : psum[tid - 1];
    if (psum[tid] >= PRE_NMS && above < PRE_NMS) {   // unique crossing chunk
        uint32_t c = above;
        int bin = base;
        for (int i = 15; i >= 0; --i) {
            c += hist[b * NBINS + base + i];
            if (c >= PRE_NMS) { bin = base + i; break; }
        }
        thr[b] = (uint32_t)bin;
    }
}

// ---- K3: compact candidates >= threshold bin (two-level aggregation) --------
__global__ void k_compact(const float* __restrict__ scores, const uint32_t* __restrict__ thr,
                          uint32_t* __restrict__ cnt, uint64_t* __restrict__ cand) {
    int b = blockIdx.y;
    int r = blockIdx.x * blockDim.x + threadIdx.x;
    __shared__ uint32_t lcnt, lbase;
    if (threadIdx.x == 0) lcnt = 0;
    __syncthreads();
    bool win = false;
    uint32_t pos = 0, k = 0, idx = 0;
    if (r < NPER) {
        int a = r / HWSZ;
        int p = r - a * HWSZ;
        float s = scores[(size_t)(b * 18 + 9 + a) * HWSZ + p];
        k = fkey(s);
        if ((k >> 18) >= thr[b]) {
            win = true;
            pos = atomicAdd(&lcnt, 1u);     // LDS atomic: cheap
            idx = (uint32_t)(p * A_NUM + a);
        }
    }
    __syncthreads();
    if (threadIdx.x == 0 && lcnt)
        lbase = atomicAdd(&cnt[b], lcnt);   // ONE global atomic per block
    __syncthreads();
    if (win) {
        uint32_t g = lbase + pos;
        if (g < CAND_CAP)
            cand[(size_t)b * CAND_CAP + g] = ((uint64_t)(~k) << 32) | (uint64_t)idx;
    }
}

// ---- K4: per-batch bitonic sort (8192, 64KB LDS) + decode top-6000 ----------
__global__ __launch_bounds__(1024) void k_sort_decode(
        const uint64_t* __restrict__ cand, const uint32_t* __restrict__ cnt,
        const float* __restrict__ deltas, const float* __restrict__ im_info,
        float4* __restrict__ boxes) {
    __shared__ uint64_t s[CAND_CAP];
    int b = blockIdx.x, tid = threadIdx.x;
    int m = (int)min(cnt[b], (uint32_t)CAND_CAP);
    for (int i = tid; i < CAND_CAP; i += 1024)
        s[i] = (i < m) ? cand[(size_t)b * CAND_CAP + i] : ~0ull;
    __syncthreads();
    for (unsigned k = 2; k <= CAND_CAP; k <<= 1) {
        for (unsigned j = k >> 1; j; j >>= 1) {
            for (unsigned p = tid; p < CAND_CAP / 2; p += 1024) {
                unsigned i = ((p & ~(j - 1)) << 1) | (p & (j - 1));
                unsigned ixj = i | j;
                uint64_t x = s[i], y = s[ixj];
                bool up = ((i & k) == 0);
                bool sw = up ? (x > y) : (x < y);
                if (sw) { s[i] = y; s[ixj] = x; }
            }
            __syncthreads();
        }
    }
    float him = im_info[b * 3 + 0], wim = im_info[b * 3 + 1];
    float ymax = __fsub_rn(him, 1.0f), xmax = __fsub_rn(wim, 1.0f);
    for (int r0 = tid; r0 < PRE_NMS; r0 += 1024) {
        uint32_t idx = (uint32_t)s[r0];
        float4 bx = make_float4(0.f, 0.f, 0.f, 0.f);
        if (idx < NPER) {
            int a = idx % A_NUM;
            int p = idx / A_NUM;
            int wc = p % W_FEAT, hr = p / W_FEAT;
            float ax1 = ANC[a][0] + (float)(wc * 16);
            float ay1 = ANC[a][1] + (float)(hr * 16);
            float ax2 = ANC[a][2] + (float)(wc * 16);
            float ay2 = ANC[a][3] + (float)(hr * 16);
            const float* dp = deltas + (size_t)(b * 36 + a * 4) * HWSZ + p;
            float dx = dp[0], dy = dp[HWSZ], dw = dp[2 * HWSZ], dh = dp[3 * HWSZ];
            float ww = __fadd_rn(__fsub_rn(ax2, ax1), 1.0f);
            float hh = __fadd_rn(__fsub_rn(ay2, ay1), 1.0f);
            float cx = __fadd_rn(ax1, __fmul_rn(0.5f, ww));
            float cy = __fadd_rn(ay1, __fmul_rn(0.5f, hh));
            float pcx = __fadd_rn(__fmul_rn(dx, ww), cx);
            float pcy = __fadd_rn(__fmul_rn(dy, hh), cy);
            float ew = (float)exp((double)dw);
            float eh = (float)exp((double)dh);
            float pw = __fmul_rn(ew, ww);
            float ph = __fmul_rn(eh, hh);
            float x1 = __fsub_rn(pcx, __fmul_rn(0.5f, pw));
            float y1 = __fsub_rn(pcy, __fmul_rn(0.5f, ph));
            float x2 = __fadd_rn(pcx, __fmul_rn(0.5f, pw));
            float y2 = __fadd_rn(pcy, __fmul_rn(0.5f, ph));
            bx.x = fminf(fmaxf(x1, 0.0f), xmax);
            bx.y = fminf(fmaxf(y1, 0.0f), ymax);
            bx.z = fminf(fmaxf(x2, 0.0f), xmax);
            bx.w = fminf(fmaxf(y2, 0.0f), ymax);
        }
        boxes[(size_t)b * PRE_NMS + r0] = bx;
    }
}

// ---- K5: exact greedy NMS, chunked-parallel (512 thr = 8 waves / batch) -----
__global__ __launch_bounds__(NMSB) void k_nms(const float4* __restrict__ boxes,
                                              float* __restrict__ out) {
    int b = blockIdx.x, tid = threadIdx.x;
    int lane = tid & 63, wv = tid >> 6;
    __shared__ float4 kbox[POST_NMS];
    __shared__ float  karea[POST_NMS];
    __shared__ float4 abox[NMSB];
    __shared__ float  aarea[NMSB];
    __shared__ uint64_t supp[NMSB][NMSB / 64];   // 512 x 8 u64 = 32 KB
    __shared__ uint32_t wcnt[NMSB / 64];
    const float4* bb = boxes + (size_t)b * PRE_NMS;
    int K = 0;   // uniform across all threads (resolve is redundant-uniform)

    for (int c0 = 0; c0 < PRE_NMS; c0 += NMSB) {
        int idx = c0 + tid;
        bool viol = (idx >= PRE_NMS);
        float4 cb = make_float4(0.f, 0.f, 0.f, 0.f);
        if (!viol) cb = bb[idx];
        float ca = area_of(cb);

        // (1) check vs kept snapshot [0..K) — the dominant parallel work
        for (int k = 0; k < K; ++k) {
            if (__all((int)viol)) break;         // wave-local early out
            float4 q = kbox[k];
            float qa = karea[k];
            viol |= iou_gt(q, qa, cb, ca);
        }

        // (2) order-preserving compaction of survivors
        uint64_t bal = __ballot((int)(!viol));
        if (lane == 0) wcnt[wv] = (uint32_t)__popcll(bal);
        __syncthreads();
        int base = 0;
        for (int w = 0; w < wv; ++w) base += (int)wcnt[w];
        int na = base;
        for (int w = wv; w < NMSB / 64; ++w) na += (int)wcnt[w];
        if (!viol) {
            int slot = base + (int)__popcll(bal & ((1ull << lane) - 1ull));
            abox[slot] = cb;
            aarea[slot] = ca;
        }
        __syncthreads();

        if (na > 0) {
            // (3) pairwise masks among survivors (thread t owns survivor t)
            uint64_t sm[NMSB / 64];
            for (int w = 0; w < NMSB / 64; ++w) sm[w] = 0ull;
            if (tid < na) {
                float4 mb = abox[tid];
                float ma = aarea[tid];
                for (int s = 0; s < tid; ++s) {
                    if (iou_gt(abox[s], aarea[s], mb, ma))
                        sm[s >> 6] |= (1ull << (s & 63));
                }
                for (int w = 0; w < NMSB / 64; ++w) supp[tid][w] = sm[w];
            }
            __syncthreads();

            // (4) uniform serial resolve (all threads redundantly; tid0 writes)
            uint64_t kl[NMSB / 64];
            for (int w = 0; w < NMSB / 64; ++w) kl[w] = 0ull;
            int nw = (na + 63) >> 6;
            for (int i = 0; i < na; ++i) {
                bool sup = false;
                for (int w = 0; w < nw; ++w) sup |= (supp[i][w] & kl[w]) != 0ull;
                if (!sup) {
                    if (tid == 0) { kbox[K] = abox[i]; karea[K] = aarea[i]; }
                    kl[i >> 6] |= (1ull << (i & 63));
                    ++K;
                    if (K >= POST_NMS) break;
                }
            }
            __syncthreads();   // kbox/karea visible before next chunk
        }
        if (K >= POST_NMS) break;
    }

    for (int r = tid; r < POST_NMS; r += NMSB) {
        float* o = out + (size_t)(b * POST_NMS + r) * 5;
        if (r < K) {
            float4 c = kbox[r];
            o[0] = (float)b; o[1] = c.x; o[2] = c.y; o[3] = c.z; o[4] = c.w;
        } else {
            o[0] = (float)b; o[1] = 0.f; o[2] = 0.f; o[3] = 0.f; o[4] = 0.f;
        }
    }
}

extern "C" void kernel_launch(void* const* d_in, const int* in_sizes, int n_in,
                              void* d_out, int out_size, void* d_ws, size_t ws_size,
                              hipStream_t stream) {
    const float* scores  = (const float*)d_in[0];
    const float* deltas  = (const float*)d_in[1];
    const float* im_info = (const float*)d_in[2];
    float* out = (float*)d_out;
    char* ws = (char*)d_ws;

    uint32_t* hist = (uint32_t*)(ws);                 // 16*16384*4 = 1,048,576
    uint32_t* cnt  = (uint32_t*)(ws + 1048576);       // 64
    uint32_t* thr  = (uint32_t*)(ws + 1048640);       // 64
    uint64_t* cand = (uint64_t*)(ws + 1048704);       // 16*8192*8 = 1,048,576
    float4*   boxes= (float4*)  (ws + 2097280);       // 16*6000*16 = 1,536,000

    hipMemsetAsync(ws, 0, 1048640, stream);           // hist + cnt

    dim3 grid2d((NPER + 255) / 256, B_NUM);
    k_hist<<<grid2d, 256, 0, stream>>>(scores, hist);
    k_scan<<<B_NUM, 1024, 0, stream>>>(hist, thr);
    k_compact<<<grid2d, 256, 0, stream>>>(scores, thr, cnt, cand);
    k_sort_decode<<<B_NUM, 1024, 0, stream>>>(cand, cnt, deltas, im_info, boxes);
    k_nms<<<B_NUM, NMSB, 0, stream>>>(boxes, out);
}

// Round 5
// 617.305 us; speedup vs baseline: 1.1366x; 1.1366x over previous
//
#include <hip/hip_runtime.h>
#include <cstdint>
#include <cmath>

#define HWSZ    15000      // H*W = 100*150
#define W_FEAT  150
#define A_NUM   9
#define NPER    135000     // A_NUM * HWSZ
#define B_NUM   16
#define PRE_NMS 6000
#define POST_NMS 300
#define NBINS   16384      // top-14-bit histogram
#define CAND_CAP 8192

// 9 base anchors from generate_anchors(16,[0.5,1,2],[8,16,32]).
__device__ __constant__ float ANC[9][4] = {
    {-84.f,  -40.f,  99.f,  55.f},
    {-176.f, -88.f, 191.f, 103.f},
    {-360.f,-184.f, 375.f, 199.f},
    {-56.f,  -56.f,  71.f,  71.f},
    {-120.f,-120.f, 135.f, 135.f},
    {-248.f,-248.f, 263.f, 263.f},
    {-36.f,  -80.f,  51.f,  95.f},
    {-80.f, -168.f,  95.f, 183.f},
    {-168.f,-344.f, 183.f, 359.f}};

__device__ __forceinline__ uint32_t fkey(float s) {
    uint32_t u = __float_as_uint(s);
    return (u & 0x80000000u) ? ~u : (u | 0x80000000u);  // monotone key
}

__device__ __forceinline__ bool iou_gt(const float4& q, float qa,
                                       const float4& c, float ca) {
    float xx1 = fmaxf(q.x, c.x);
    float yy1 = fmaxf(q.y, c.y);
    float xx2 = fminf(q.z, c.z);
    float yy2 = fminf(q.w, c.w);
    float iw = fmaxf(0.0f, __fadd_rn(__fsub_rn(xx2, xx1), 1.0f));
    float ih = fmaxf(0.0f, __fadd_rn(__fsub_rn(yy2, yy1), 1.0f));
    float inter = __fmul_rn(iw, ih);
    float den = __fsub_rn(__fadd_rn(qa, ca), inter);
    return __fdiv_rn(inter, den) > 0.7f;
}

__device__ __forceinline__ float area_of(const float4& c) {
    return __fmul_rn(__fadd_rn(__fsub_rn(c.z, c.x), 1.0f),
                     __fadd_rn(__fsub_rn(c.w, c.y), 1.0f));
}

// ---- K1: per-batch histogram, nsub sub-histograms to spread atomic traffic --
__global__ void k_hist(const float* __restrict__ scores, uint32_t* __restrict__ hist,
                       int nsub) {
    int b = blockIdx.y;
    int r = blockIdx.x * blockDim.x + threadIdx.x;
    if (r >= NPER) return;
    int sub = blockIdx.x & (nsub - 1);
    int a = r / HWSZ;
    int p = r - a * HWSZ;
    float s = scores[(size_t)(b * 18 + 9 + a) * HWSZ + p];
    atomicAdd(&hist[((size_t)b * nsub + sub) * NBINS + (fkey(s) >> 18)], 1u);
}

// ---- K2: threshold bin via single-pass suffix scan (1024 thr) ---------------
__global__ __launch_bounds__(1024) void k_scan(const uint32_t* __restrict__ hist,
                                               uint32_t* __restrict__ thr, int nsub) {
    int b = blockIdx.x, tid = threadIdx.x;
    const uint32_t* h = hist + (size_t)b * nsub * NBINS;
    __shared__ uint32_t psum[1024];
    int base = NBINS - 16 * (tid + 1);
    uint32_t s = 0;
    for (int u = 0; u < nsub; ++u)
        for (int i = 0; i < 16; ++i) s += h[u * NBINS + base + i];
    psum[tid] = s;
    __syncthreads();
    for (int off = 1; off < 1024; off <<= 1) {   // cum-from-top over chunks
        uint32_t v = (tid >= off) ? psum[tid - off] : 0u;
        __syncthreads();
        psum[tid] += v;
        __syncthreads();
    }
    uint32_t above = (tid == 0) ? 0u : psum[tid - 1];
    if (psum[tid] >= PRE_NMS && above < PRE_NMS) {   // unique crossing chunk
        uint32_t c = above;
        int bin = base;
        for (int i = 15; i >= 0; --i) {
            uint32_t bc = 0;
            for (int u = 0; u < nsub; ++u) bc += h[u * NBINS + base + i];
            c += bc;
            if (c >= PRE_NMS) { bin = base + i; break; }
        }
        thr[b] = (uint32_t)bin;
    }
}

// ---- K3: compact candidates >= threshold bin (two-level aggregation) --------
__global__ void k_compact(const float* __restrict__ scores, const uint32_t* __restrict__ thr,
                          uint32_t* __restrict__ cnt, uint64_t* __restrict__ cand) {
    int b = blockIdx.y;
    int r = blockIdx.x * blockDim.x + threadIdx.x;
    __shared__ uint32_t lcnt, lbase;
    if (threadIdx.x == 0) lcnt = 0;
    __syncthreads();
    bool win = false;
    uint32_t pos = 0, k = 0, idx = 0;
    if (r < NPER) {
        int a = r / HWSZ;
        int p = r - a * HWSZ;
        float s = scores[(size_t)(b * 18 + 9 + a) * HWSZ + p];
        k = fkey(s);
        if ((k >> 18) >= thr[b]) {
            win = true;
            pos = atomicAdd(&lcnt, 1u);
            idx = (uint32_t)(p * A_NUM + a);
        }
    }
    __syncthreads();
    if (threadIdx.x == 0 && lcnt)
        lbase = atomicAdd(&cnt[b], lcnt);
    __syncthreads();
    if (win) {
        uint32_t g = lbase + pos;
        if (g < CAND_CAP)
            cand[(size_t)b * CAND_CAP + g] = ((uint64_t)(~k) << 32) | (uint64_t)idx;
    }
}

// ---- K4: per-batch bitonic sort (8192, 64KB LDS) + decode top-6000 ----------
__global__ __launch_bounds__(1024) void k_sort_decode(
        const uint64_t* __restrict__ cand, const uint32_t* __restrict__ cnt,
        const float* __restrict__ deltas, const float* __restrict__ im_info,
        float4* __restrict__ boxes) {
    __shared__ uint64_t s[CAND_CAP];
    int b = blockIdx.x, tid = threadIdx.x;
    int m = (int)min(cnt[b], (uint32_t)CAND_CAP);
    for (int i = tid; i < CAND_CAP; i += 1024)
        s[i] = (i < m) ? cand[(size_t)b * CAND_CAP + i] : ~0ull;
    __syncthreads();
    for (unsigned k = 2; k <= CAND_CAP; k <<= 1) {
        for (unsigned j = k >> 1; j; j >>= 1) {
            for (unsigned p = tid; p < CAND_CAP / 2; p += 1024) {
                unsigned i = ((p & ~(j - 1)) << 1) | (p & (j - 1));
                unsigned ixj = i | j;
                uint64_t x = s[i], y = s[ixj];
                bool up = ((i & k) == 0);
                bool sw = up ? (x > y) : (x < y);
                if (sw) { s[i] = y; s[ixj] = x; }
            }
            __syncthreads();
        }
    }
    float him = im_info[b * 3 + 0], wim = im_info[b * 3 + 1];
    float ymax = __fsub_rn(him, 1.0f), xmax = __fsub_rn(wim, 1.0f);
    for (int r0 = tid; r0 < PRE_NMS; r0 += 1024) {
        uint32_t idx = (uint32_t)s[r0];
        float4 bx = make_float4(0.f, 0.f, 0.f, 0.f);
        if (idx < NPER) {
            int a = idx % A_NUM;
            int p = idx / A_NUM;
            int wc = p % W_FEAT, hr = p / W_FEAT;
            float ax1 = ANC[a][0] + (float)(wc * 16);
            float ay1 = ANC[a][1] + (float)(hr * 16);
            float ax2 = ANC[a][2] + (float)(wc * 16);
            float ay2 = ANC[a][3] + (float)(hr * 16);
            const float* dp = deltas + (size_t)(b * 36 + a * 4) * HWSZ + p;
            float dx = dp[0], dy = dp[HWSZ], dw = dp[2 * HWSZ], dh = dp[3 * HWSZ];
            float ww = __fadd_rn(__fsub_rn(ax2, ax1), 1.0f);
            float hh = __fadd_rn(__fsub_rn(ay2, ay1), 1.0f);
            float cx = __fadd_rn(ax1, __fmul_rn(0.5f, ww));
            float cy = __fadd_rn(ay1, __fmul_rn(0.5f, hh));
            float pcx = __fadd_rn(__fmul_rn(dx, ww), cx);
            float pcy = __fadd_rn(__fmul_rn(dy, hh), cy);
            float ew = (float)exp((double)dw);
            float eh = (float)exp((double)dh);
            float pw = __fmul_rn(ew, ww);
            float ph = __fmul_rn(eh, hh);
            float x1 = __fsub_rn(pcx, __fmul_rn(0.5f, pw));
            float y1 = __fsub_rn(pcy, __fmul_rn(0.5f, ph));
            float x2 = __fadd_rn(pcx, __fmul_rn(0.5f, pw));
            float y2 = __fadd_rn(pcy, __fmul_rn(0.5f, ph));
            bx.x = fminf(fmaxf(x1, 0.0f), xmax);
            bx.y = fminf(fmaxf(y1, 0.0f), ymax);
            bx.z = fminf(fmaxf(x2, 0.0f), xmax);
            bx.w = fminf(fmaxf(y2, 0.0f), ymax);
        }
        boxes[(size_t)b * PRE_NMS + r0] = bx;
    }
}

// ---- K5: exact greedy NMS, single wave, barrier-free, kept-list in registers.
// kept[s*64+lane] lives in lane-cycled registers k0..k4 (K <= 300 => 5 slots).
#define PROC(P)                                                                \
    do {                                                                       \
        float ca = area_of(P);                                                 \
        bool viol = false;                                                     \
        if (K > 0)   viol |= (lane       < K) & iou_gt(k0, a0, P, ca);         \
        if (K > 64)  viol |= (lane + 64  < K) & iou_gt(k1, a1, P, ca);         \
        if (K > 128) viol |= (lane + 128 < K) & iou_gt(k2, a2, P, ca);         \
        if (K > 192) viol |= (lane + 192 < K) & iou_gt(k3, a3, P, ca);         \
        if (K > 256) viol |= (lane + 256 < K) & iou_gt(k4, a4, P, ca);         \
        if (!__any((int)viol)) {                                               \
            int sl = K >> 6, tg = K & 63;                                      \
            if (lane == tg) {                                                  \
                switch (sl) {                                                  \
                case 0: k0 = P; a0 = ca; break;                                \
                case 1: k1 = P; a1 = ca; break;                                \
                case 2: k2 = P; a2 = ca; break;                                \
                case 3: k3 = P; a3 = ca; break;                                \
                default: k4 = P; a4 = ca; break;                               \
                }                                                              \
            }                                                                  \
            ++K;                                                               \
        }                                                                      \
    } while (0)

__global__ __launch_bounds__(64) void k_nms(const float4* __restrict__ boxes,
                                            float* __restrict__ out) {
    int b = blockIdx.x, lane = threadIdx.x;
    const float4* bb = boxes + (size_t)b * PRE_NMS;

    // warm local L2/L1 with this batch's 96KB of boxes (coalesced stream)
    for (int i = lane; i < PRE_NMS; i += 64) {
        float4 t = bb[i];
        asm volatile("" :: "v"(t.x), "v"(t.y), "v"(t.z), "v"(t.w));
    }

    float4 k0 = {}, k1 = {}, k2 = {}, k3 = {}, k4 = {};
    float a0 = 0.f, a1 = 0.f, a2 = 0.f, a3 = 0.f, a4 = 0.f;
    int K = 0;

    // 4-deep software prefetch, hand-unrolled x4 (static register names)
    float4 p0 = bb[0], p1 = bb[1], p2 = bb[2], p3 = bb[3];
    bool done = false;
    for (int r = 0; r < PRE_NMS && !done; r += 4) {
        int n = r + 4;
        float4 n0 = bb[(n + 0 < PRE_NMS) ? n + 0 : PRE_NMS - 1];
        float4 n1 = bb[(n + 1 < PRE_NMS) ? n + 1 : PRE_NMS - 1];
        float4 n2 = bb[(n + 2 < PRE_NMS) ? n + 2 : PRE_NMS - 1];
        float4 n3 = bb[(n + 3 < PRE_NMS) ? n + 3 : PRE_NMS - 1];
        PROC(p0); if (K >= POST_NMS) done = true;
        if (!done) { PROC(p1); if (K >= POST_NMS) done = true; }
        if (!done) { PROC(p2); if (K >= POST_NMS) done = true; }
        if (!done) { PROC(p3); if (K >= POST_NMS) done = true; }
        p0 = n0; p1 = n1; p2 = n2; p3 = n3;
    }

    // output: kept[s*64+lane]
#pragma unroll
    for (int s = 0; s < 5; ++s) {
        int idx = s * 64 + lane;
        if (idx < POST_NMS) {
            float4 c;
            switch (s) {
            case 0: c = k0; break;
            case 1: c = k1; break;
            case 2: c = k2; break;
            case 3: c = k3; break;
            default: c = k4; break;
            }
            bool v = idx < K;
            float* o = out + (size_t)(b * POST_NMS + idx) * 5;
            o[0] = (float)b;
            o[1] = v ? c.x : 0.f;
            o[2] = v ? c.y : 0.f;
            o[3] = v ? c.z : 0.f;
            o[4] = v ? c.w : 0.f;
        }
    }
}

extern "C" void kernel_launch(void* const* d_in, const int* in_sizes, int n_in,
                              void* d_out, int out_size, void* d_ws, size_t ws_size,
                              hipStream_t stream) {
    const float* scores  = (const float*)d_in[0];
    const float* deltas  = (const float*)d_in[1];
    const float* im_info = (const float*)d_in[2];
    float* out = (float*)d_out;
    char* ws = (char*)d_ws;

    int nsub = 4;
    size_t histBytes = (size_t)B_NUM * nsub * NBINS * 4;
    size_t need = histBytes + 128 + (size_t)B_NUM * CAND_CAP * 8
                  + (size_t)B_NUM * PRE_NMS * 16;
    if (ws_size < need) { nsub = 1; histBytes = (size_t)B_NUM * NBINS * 4; }

    uint32_t* hist = (uint32_t*)(ws);
    uint32_t* cnt  = (uint32_t*)(ws + histBytes);
    uint32_t* thr  = (uint32_t*)(ws + histBytes + 64);
    uint64_t* cand = (uint64_t*)(ws + histBytes + 128);
    float4*   boxes= (float4*)  (ws + histBytes + 128 + (size_t)B_NUM * CAND_CAP * 8);

    hipMemsetAsync(ws, 0, histBytes + 64, stream);    // hist + cnt

    dim3 grid2d((NPER + 255) / 256, B_NUM);
    k_hist<<<grid2d, 256, 0, stream>>>(scores, hist, nsub);
    k_scan<<<B_NUM, 1024, 0, stream>>>(hist, thr, nsub);
    k_compact<<<grid2d, 256, 0, stream>>>(scores, thr, cnt, cand);
    k_sort_decode<<<B_NUM, 1024, 0, stream>>>(cand, cnt, deltas, im_info, boxes);
    k_nms<<<B_NUM, 64, 0, stream>>>(boxes, out);
}

// Round 6
// 529.076 us; speedup vs baseline: 1.3261x; 1.1668x over previous
//
#include <hip/hip_runtime.h>
#include <cstdint>
#include <cmath>

#define HWSZ    15000      // H*W = 100*150
#define W_FEAT  150
#define A_NUM   9
#define NPER    135000     // A_NUM * HWSZ
#define B_NUM   16
#define PRE_NMS 6000
#define POST_NMS 300
#define NBINS   16384      // top-14-bit histogram
#define CAND_CAP 8192

// 9 base anchors from generate_anchors(16,[0.5,1,2],[8,16,32]).
__device__ __constant__ float ANC[9][4] = {
    {-84.f,  -40.f,  99.f,  55.f},
    {-176.f, -88.f, 191.f, 103.f},
    {-360.f,-184.f, 375.f, 199.f},
    {-56.f,  -56.f,  71.f,  71.f},
    {-120.f,-120.f, 135.f, 135.f},
    {-248.f,-248.f, 263.f, 263.f},
    {-36.f,  -80.f,  51.f,  95.f},
    {-80.f, -168.f,  95.f, 183.f},
    {-168.f,-344.f, 183.f, 359.f}};

__device__ __forceinline__ uint32_t fkey(float s) {
    uint32_t u = __float_as_uint(s);
    return (u & 0x80000000u) ? ~u : (u | 0x80000000u);  // monotone key
}

__device__ __forceinline__ bool iou_gt(const float4& q, float qa,
                                       const float4& c, float ca) {
    float xx1 = fmaxf(q.x, c.x);
    float yy1 = fmaxf(q.y, c.y);
    float xx2 = fminf(q.z, c.z);
    float yy2 = fminf(q.w, c.w);
    float iw = fmaxf(0.0f, __fadd_rn(__fsub_rn(xx2, xx1), 1.0f));
    float ih = fmaxf(0.0f, __fadd_rn(__fsub_rn(yy2, yy1), 1.0f));
    float inter = __fmul_rn(iw, ih);
    float den = __fsub_rn(__fadd_rn(qa, ca), inter);
    return __fdiv_rn(inter, den) > 0.7f;
}

__device__ __forceinline__ float area_of(const float4& c) {
    return __fmul_rn(__fadd_rn(__fsub_rn(c.z, c.x), 1.0f),
                     __fadd_rn(__fsub_rn(c.w, c.y), 1.0f));
}

// ---- K1: per-batch histogram, nsub sub-histograms to spread atomic traffic --
__global__ void k_hist(const float* __restrict__ scores, uint32_t* __restrict__ hist,
                       int nsub) {
    int b = blockIdx.y;
    int r = blockIdx.x * blockDim.x + threadIdx.x;
    if (r >= NPER) return;
    int sub = blockIdx.x & (nsub - 1);
    int a = r / HWSZ;
    int p = r - a * HWSZ;
    float s = scores[(size_t)(b * 18 + 9 + a) * HWSZ + p];
    atomicAdd(&hist[((size_t)b * nsub + sub) * NBINS + (fkey(s) >> 18)], 1u);
}

// ---- K2: threshold bin via single-pass suffix scan (1024 thr) ---------------
__global__ __launch_bounds__(1024) void k_scan(const uint32_t* __restrict__ hist,
                                               uint32_t* __restrict__ thr, int nsub) {
    int b = blockIdx.x, tid = threadIdx.x;
    const uint32_t* h = hist + (size_t)b * nsub * NBINS;
    __shared__ uint32_t psum[1024];
    int base = NBINS - 16 * (tid + 1);
    uint32_t s = 0;
    for (int u = 0; u < nsub; ++u)
        for (int i = 0; i < 16; ++i) s += h[u * NBINS + base + i];
    psum[tid] = s;
    __syncthreads();
    for (int off = 1; off < 1024; off <<= 1) {   // cum-from-top over chunks
        uint32_t v = (tid >= off) ? psum[tid - off] : 0u;
        __syncthreads();
        psum[tid] += v;
        __syncthreads();
    }
    uint32_t above = (tid == 0) ? 0u : psum[tid - 1];
    if (psum[tid] >= PRE_NMS && above < PRE_NMS) {   // unique crossing chunk
        uint32_t c = above;
        int bin = base;
        for (int i = 15; i >= 0; --i) {
            uint32_t bc = 0;
            for (int u = 0; u < nsub; ++u) bc += h[u * NBINS + base + i];
            c += bc;
            if (c >= PRE_NMS) { bin = base + i; break; }
        }
        thr[b] = (uint32_t)bin;
    }
}

// ---- K3: compact candidates >= threshold bin (two-level aggregation) --------
__global__ void k_compact(const float* __restrict__ scores, const uint32_t* __restrict__ thr,
                          uint32_t* __restrict__ cnt, uint64_t* __restrict__ cand) {
    int b = blockIdx.y;
    int r = blockIdx.x * blockDim.x + threadIdx.x;
    __shared__ uint32_t lcnt, lbase;
    if (threadIdx.x == 0) lcnt = 0;
    __syncthreads();
    bool win = false;
    uint32_t pos = 0, k = 0, idx = 0;
    if (r < NPER) {
        int a = r / HWSZ;
        int p = r - a * HWSZ;
        float s = scores[(size_t)(b * 18 + 9 + a) * HWSZ + p];
        k = fkey(s);
        if ((k >> 18) >= thr[b]) {
            win = true;
            pos = atomicAdd(&lcnt, 1u);
            idx = (uint32_t)(p * A_NUM + a);
        }
    }
    __syncthreads();
    if (threadIdx.x == 0 && lcnt)
        lbase = atomicAdd(&cnt[b], lcnt);
    __syncthreads();
    if (win) {
        uint32_t g = lbase + pos;
        if (g < CAND_CAP)
            cand[(size_t)b * CAND_CAP + g] = ((uint64_t)(~k) << 32) | (uint64_t)idx;
    }
}

// ---- K4: per-batch bitonic sort (8192, 64KB LDS) + decode top-6000 ----------
__global__ __launch_bounds__(1024) void k_sort_decode(
        const uint64_t* __restrict__ cand, const uint32_t* __restrict__ cnt,
        const float* __restrict__ deltas, const float* __restrict__ im_info,
        float4* __restrict__ boxes) {
    __shared__ uint64_t s[CAND_CAP];
    int b = blockIdx.x, tid = threadIdx.x;
    int m = (int)min(cnt[b], (uint32_t)CAND_CAP);
    for (int i = tid; i < CAND_CAP; i += 1024)
        s[i] = (i < m) ? cand[(size_t)b * CAND_CAP + i] : ~0ull;
    __syncthreads();
    for (unsigned k = 2; k <= CAND_CAP; k <<= 1) {
        for (unsigned j = k >> 1; j; j >>= 1) {
            for (unsigned p = tid; p < CAND_CAP / 2; p += 1024) {
                unsigned i = ((p & ~(j - 1)) << 1) | (p & (j - 1));
                unsigned ixj = i | j;
                uint64_t x = s[i], y = s[ixj];
                bool up = ((i & k) == 0);
                bool sw = up ? (x > y) : (x < y);
                if (sw) { s[i] = y; s[ixj] = x; }
            }
            __syncthreads();
        }
    }
    float him = im_info[b * 3 + 0], wim = im_info[b * 3 + 1];
    float ymax = __fsub_rn(him, 1.0f), xmax = __fsub_rn(wim, 1.0f);
    for (int r0 = tid; r0 < PRE_NMS; r0 += 1024) {
        uint32_t idx = (uint32_t)s[r0];
        float4 bx = make_float4(0.f, 0.f, 0.f, 0.f);
        if (idx < NPER) {
            int a = idx % A_NUM;
            int p = idx / A_NUM;
            int wc = p % W_FEAT, hr = p / W_FEAT;
            float ax1 = ANC[a][0] + (float)(wc * 16);
            float ay1 = ANC[a][1] + (float)(hr * 16);
            float ax2 = ANC[a][2] + (float)(wc * 16);
            float ay2 = ANC[a][3] + (float)(hr * 16);
            const float* dp = deltas + (size_t)(b * 36 + a * 4) * HWSZ + p;
            float dx = dp[0], dy = dp[HWSZ], dw = dp[2 * HWSZ], dh = dp[3 * HWSZ];
            float ww = __fadd_rn(__fsub_rn(ax2, ax1), 1.0f);
            float hh = __fadd_rn(__fsub_rn(ay2, ay1), 1.0f);
            float cx = __fadd_rn(ax1, __fmul_rn(0.5f, ww));
            float cy = __fadd_rn(ay1, __fmul_rn(0.5f, hh));
            float pcx = __fadd_rn(__fmul_rn(dx, ww), cx);
            float pcy = __fadd_rn(__fmul_rn(dy, hh), cy);
            float ew = (float)exp((double)dw);
            float eh = (float)exp((double)dh);
            float pw = __fmul_rn(ew, ww);
            float ph = __fmul_rn(eh, hh);
            float x1 = __fsub_rn(pcx, __fmul_rn(0.5f, pw));
            float y1 = __fsub_rn(pcy, __fmul_rn(0.5f, ph));
            float x2 = __fadd_rn(pcx, __fmul_rn(0.5f, pw));
            float y2 = __fadd_rn(pcy, __fmul_rn(0.5f, ph));
            bx.x = fminf(fmaxf(x1, 0.0f), xmax);
            bx.y = fminf(fmaxf(y1, 0.0f), ymax);
            bx.z = fminf(fmaxf(x2, 0.0f), xmax);
            bx.w = fminf(fmaxf(y2, 0.0f), ymax);
        }
        boxes[(size_t)b * PRE_NMS + r0] = bx;
    }
}

// ---- K5a: suppression bitmask for first NC candidates (64x64 wave tiles) ----
// masks[(b*NW + tj)*NC + i] = bits jj where j=tj*64+jj > i and IoU(i,j) > 0.7
__global__ __launch_bounds__(256) void k_mask(const float4* __restrict__ boxes,
                                              uint64_t* __restrict__ masks,
                                              int NC, int NW, int T) {
    int b = blockIdx.y;
    int wv = threadIdx.x >> 6, lane = threadIdx.x & 63;
    int t = blockIdx.x * 4 + wv;
    if (t >= T) return;
    int ti = 0, rem = t;
    while (rem >= NW - ti) { rem -= NW - ti; ++ti; }   // upper-triangle map
    int tj = ti + rem;
    __shared__ float4 colb[4][64];
    __shared__ float  cola[4][64];
    const float4* bb = boxes + (size_t)b * PRE_NMS;
    int i = ti * 64 + lane;
    float4 c = bb[i];
    float ca = area_of(c);
    float4 q0 = bb[tj * 64 + lane];
    colb[wv][lane] = q0;
    cola[wv][lane] = area_of(q0);
    asm volatile("s_waitcnt lgkmcnt(0)" ::: "memory");  // single-wave LDS sync
    __builtin_amdgcn_wave_barrier();
    uint64_t m = 0;
    int jbase = tj * 64;
#pragma unroll
    for (int jj = 0; jj < 64; ++jj) {
        float4 q = colb[wv][jj];
        float qa = cola[wv][jj];
        bool hit = ((jbase + jj) > i) && iou_gt(q, qa, c, ca);
        m |= ((uint64_t)(hit ? 1u : 0u)) << jj;
    }
    masks[((size_t)b * NW + tj) * NC + i] = m;
}

// kept-list register helpers (slot s holds kept[s*64+lane])
#define PROC(P)                                                                \
    do {                                                                       \
        float ca = area_of(P);                                                 \
        bool viol = false;                                                     \
        if (K > 0)   viol |= (lane       < K) & iou_gt(k0, a0, P, ca);         \
        if (K > 64)  viol |= (lane + 64  < K) & iou_gt(k1, a1, P, ca);         \
        if (K > 128) viol |= (lane + 128 < K) & iou_gt(k2, a2, P, ca);         \
        if (K > 192) viol |= (lane + 192 < K) & iou_gt(k3, a3, P, ca);         \
        if (K > 256) viol |= (lane + 256 < K) & iou_gt(k4, a4, P, ca);         \
        if (!__any((int)viol)) {                                               \
            int sl = K >> 6, tg = K & 63;                                      \
            if (lane == tg) {                                                  \
                switch (sl) {                                                  \
                case 0: k0 = P; a0 = ca; break;                                \
                case 1: k1 = P; a1 = ca; break;                                \
                case 2: k2 = P; a2 = ca; break;                                \
                case 3: k3 = P; a3 = ca; break;                                \
                default: k4 = P; a4 = ca; break;                               \
                }                                                              \
            }                                                                  \
            ++K;                                                               \
        }                                                                      \
    } while (0)

// one mask-walk step: consume ring reg RG (= row i), reload with row i+8
#define RSTEP(RG)                                                              \
    do {                                                                       \
        if (!fin && i < NC) {                                                  \
            bool mine = (lane == (i >> 6));                                    \
            bool sb = mine && ((sup >> (i & 63)) & 1ull);                      \
            if (!__any((int)sb)) {                                             \
                int sl = K >> 6, tg = K & 63;                                  \
                if (lane == tg) {                                              \
                    switch (sl) {                                              \
                    case 0: i0 = i; break;                                     \
                    case 1: i1 = i; break;                                     \
                    case 2: i2 = i; break;                                     \
                    case 3: i3 = i; break;                                     \
                    default: i4 = i; break;                                    \
                    }                                                          \
                }                                                              \
                if (lane < NW) sup |= RG;                                      \
                ++K;                                                           \
                if (K >= POST_NMS) fin = true;                                 \
            }                                                                  \
            int nx = i + 8; if (nx >= NC) nx = NC - 1;                         \
            RG = mrow[nx];                                                     \
            ++i;                                                               \
        }                                                                      \
    } while (0)

// ---- K5b: greedy resolve, one wave per batch --------------------------------
__global__ __launch_bounds__(64) void k_resolve(const float4* __restrict__ boxes,
                                                const uint64_t* __restrict__ masks,
                                                int NC, int NW,
                                                float* __restrict__ out) {
    int b = blockIdx.x, lane = threadIdx.x;
    const float4* bb = boxes + (size_t)b * PRE_NMS;
    int K = 0;
    int i0 = 0, i1 = 0, i2 = 0, i3 = 0, i4 = 0;
    bool fin = false;

    if (NC > 0) {
        const uint64_t* mrow =
            masks + ((size_t)b * NW + (lane < NW ? lane : NW - 1)) * NC;
        uint64_t sup = 0;
        uint64_t r0 = mrow[0], r1 = mrow[1], r2 = mrow[2], r3 = mrow[3];
        uint64_t r4 = mrow[4], r5 = mrow[5], r6 = mrow[6], r7 = mrow[7];
        int i = 0;
        while (i < NC && !fin) {
            RSTEP(r0); RSTEP(r1); RSTEP(r2); RSTEP(r3);
            RSTEP(r4); RSTEP(r5); RSTEP(r6); RSTEP(r7);
        }
    }

    // gather kept boxes into lane-cycled registers
    float4 k0, k1, k2, k3, k4;
    float a0, a1, a2, a3, a4;
    { int id = (lane       < K) ? i0 : 0; k0 = bb[id]; a0 = area_of(k0); }
    { int id = (lane + 64  < K) ? i1 : 0; k1 = bb[id]; a1 = area_of(k1); }
    { int id = (lane + 128 < K) ? i2 : 0; k2 = bb[id]; a2 = area_of(k2); }
    { int id = (lane + 192 < K) ? i3 : 0; k3 = bb[id]; a3 = area_of(k3); }
    { int id = (lane + 256 < K) ? i4 : 0; k4 = bb[id]; a4 = area_of(k4); }

    // fallback: continue exact greedy walk past NC if needed
    if (!fin && NC < PRE_NMS) {
        float4 p0 = bb[NC + 0], p1 = bb[NC + 1], p2 = bb[NC + 2], p3 = bb[NC + 3];
        bool done = false;
        for (int r = NC; r < PRE_NMS && !done; r += 4) {
            int n = r + 4;
            float4 n0 = bb[(n + 0 < PRE_NMS) ? n + 0 : PRE_NMS - 1];
            float4 n1 = bb[(n + 1 < PRE_NMS) ? n + 1 : PRE_NMS - 1];
            float4 n2 = bb[(n + 2 < PRE_NMS) ? n + 2 : PRE_NMS - 1];
            float4 n3 = bb[(n + 3 < PRE_NMS) ? n + 3 : PRE_NMS - 1];
            PROC(p0); if (K >= POST_NMS) done = true;
            if (!done) { PROC(p1); if (K >= POST_NMS) done = true; }
            if (!done) { PROC(p2); if (K >= POST_NMS) done = true; }
            if (!done) { PROC(p3); if (K >= POST_NMS) done = true; }
            p0 = n0; p1 = n1; p2 = n2; p3 = n3;
        }
    }

    // output kept[s*64+lane]
#pragma unroll
    for (int s = 0; s < 5; ++s) {
        int idx = s * 64 + lane;
        if (idx < POST_NMS) {
            float4 c;
            switch (s) {
            case 0: c = k0; break;
            case 1: c = k1; break;
            case 2: c = k2; break;
            case 3: c = k3; break;
            default: c = k4; break;
            }
            bool v = idx < K;
            float* o = out + (size_t)(b * POST_NMS + idx) * 5;
            o[0] = (float)b;
            o[1] = v ? c.x : 0.f;
            o[2] = v ? c.y : 0.f;
            o[3] = v ? c.z : 0.f;
            o[4] = v ? c.w : 0.f;
        }
    }
}

extern "C" void kernel_launch(void* const* d_in, const int* in_sizes, int n_in,
                              void* d_out, int out_size, void* d_ws, size_t ws_size,
                              hipStream_t stream) {
    const float* scores  = (const float*)d_in[0];
    const float* deltas  = (const float*)d_in[1];
    const float* im_info = (const float*)d_in[2];
    float* out = (float*)d_out;
    char* ws = (char*)d_ws;

    size_t candBytes = (size_t)B_NUM * CAND_CAP * 8;          // 1 MB
    size_t boxBytes  = (size_t)B_NUM * PRE_NMS * 16;          // 1.5 MB
    int nsub = 8;
    while (nsub > 1 &&
           (size_t)B_NUM * nsub * NBINS * 4 + 128 + candBytes + boxBytes > ws_size)
        nsub >>= 1;
    size_t histBytes = (size_t)B_NUM * nsub * NBINS * 4;
    size_t base = histBytes + 128 + candBytes + boxBytes;

    int NC = 0;
    {
        const int ladder[4] = {4096, 3072, 2048, 1024};
        for (int li = 0; li < 4; ++li) {
            size_t mb = (size_t)B_NUM * ladder[li] * (ladder[li] / 64) * 8;
            if (base + mb <= ws_size) { NC = ladder[li]; break; }
        }
    }
    int NW = NC / 64;

    uint32_t* hist = (uint32_t*)(ws);
    uint32_t* cnt  = (uint32_t*)(ws + histBytes);
    uint32_t* thr  = (uint32_t*)(ws + histBytes + 64);
    uint64_t* cand = (uint64_t*)(ws + histBytes + 128);
    float4*   boxes= (float4*)  (ws + histBytes + 128 + candBytes);
    uint64_t* masks= (uint64_t*)(ws + base);

    hipMemsetAsync(ws, 0, histBytes + 64, stream);    // hist + cnt

    dim3 grid2d((NPER + 255) / 256, B_NUM);
    k_hist<<<grid2d, 256, 0, stream>>>(scores, hist, nsub);
    k_scan<<<B_NUM, 1024, 0, stream>>>(hist, thr, nsub);
    k_compact<<<grid2d, 256, 0, stream>>>(scores, thr, cnt, cand);
    k_sort_decode<<<B_NUM, 1024, 0, stream>>>(cand, cnt, deltas, im_info, boxes);
    if (NC > 0) {
        int T = NW * (NW + 1) / 2;
        dim3 gm((T + 3) / 4, B_NUM);
        k_mask<<<gm, 256, 0, stream>>>(boxes, masks, NC, NW, T);
    }
    k_resolve<<<B_NUM, 64, 0, stream>>>(boxes, masks, NC, NW, out);
}

// Round 7
// 279.419 us; speedup vs baseline: 2.5110x; 1.8935x over previous
//
#include <hip/hip_runtime.h>
#include <cstdint>
#include <cmath>

#define HWSZ    15000      // H*W = 100*150
#define W_FEAT  150
#define A_NUM   9
#define NPER    135000     // A_NUM * HWSZ
#define B_NUM   16
#define PRE_NMS 6000
#define POST_NMS 300
#define NBINS   16384      // top-14-bit histogram
#define CAND_CAP 8192

// 9 base anchors from generate_anchors(16,[0.5,1,2],[8,16,32]).
__device__ __constant__ float ANC[9][4] = {
    {-84.f,  -40.f,  99.f,  55.f},
    {-176.f, -88.f, 191.f, 103.f},
    {-360.f,-184.f, 375.f, 199.f},
    {-56.f,  -56.f,  71.f,  71.f},
    {-120.f,-120.f, 135.f, 135.f},
    {-248.f,-248.f, 263.f, 263.f},
    {-36.f,  -80.f,  51.f,  95.f},
    {-80.f, -168.f,  95.f, 183.f},
    {-168.f,-344.f, 183.f, 359.f}};

__device__ __forceinline__ uint32_t fkey(float s) {
    uint32_t u = __float_as_uint(s);
    return (u & 0x80000000u) ? ~u : (u | 0x80000000u);  // monotone key
}

// EXACT replacement for  __fdiv_rn(inter,den) > 0.7f :
//   rn(inter/den) > 0.7f  <=>  inter/den >= m,  m = midpoint(0.7f, next(0.7f))
//   (tie rounds to even = 0x3F333334 > 0.7f, hence >=).  m = 0x1.666667p-1 has
//   25 mantissa bits; den has 24 -> m*(double)den is EXACT (49 <= 53 bits).
__device__ __forceinline__ bool iou_gt(const float4& q, float qa,
                                       const float4& c, float ca) {
    float xx1 = fmaxf(q.x, c.x);
    float yy1 = fmaxf(q.y, c.y);
    float xx2 = fminf(q.z, c.z);
    float yy2 = fminf(q.w, c.w);
    float iw = fmaxf(0.0f, __fadd_rn(__fsub_rn(xx2, xx1), 1.0f));
    float ih = fmaxf(0.0f, __fadd_rn(__fsub_rn(yy2, yy1), 1.0f));
    float inter = __fmul_rn(iw, ih);
    float den = __fsub_rn(__fadd_rn(qa, ca), inter);
    return (double)inter >= 0x1.666667p-1 * (double)den;
}

__device__ __forceinline__ float area_of(const float4& c) {
    return __fmul_rn(__fadd_rn(__fsub_rn(c.z, c.x), 1.0f),
                     __fadd_rn(__fsub_rn(c.w, c.y), 1.0f));
}

// ---- K1: fused per-batch selection: hist -> scan -> compact -> sort -> decode
__global__ __launch_bounds__(1024) void k_select(
        const float* __restrict__ scores, const float* __restrict__ deltas,
        const float* __restrict__ im_info, float4* __restrict__ boxes) {
    __shared__ uint64_t s[CAND_CAP];          // 64KB; aliased as hist u32[16384]
    __shared__ uint32_t psum[1024];
    __shared__ uint32_t thrbin, lcnt;
    uint32_t* hist = (uint32_t*)s;
    int b = blockIdx.x, tid = threadIdx.x;

    for (int i = tid; i < NBINS; i += 1024) hist[i] = 0;
    if (tid == 0) lcnt = 0;
    __syncthreads();

    // pass 1: LDS histogram of the contiguous fg-score block (float4 loads)
    const float4* sc4 = (const float4*)(scores + (size_t)(b * 18 + 9) * HWSZ);
    for (int i = tid; i < NPER / 4; i += 1024) {
        float4 v = sc4[i];
        atomicAdd(&hist[fkey(v.x) >> 18], 1u);
        atomicAdd(&hist[fkey(v.y) >> 18], 1u);
        atomicAdd(&hist[fkey(v.z) >> 18], 1u);
        atomicAdd(&hist[fkey(v.w) >> 18], 1u);
    }
    __syncthreads();

    // threshold bin: cum-from-top >= PRE_NMS (16 bins per thread + block scan)
    int base = NBINS - 16 * (tid + 1);
    uint32_t acc = 0;
    for (int i = 0; i < 16; ++i) acc += hist[base + i];
    psum[tid] = acc;
    __syncthreads();
    for (int off = 1; off < 1024; off <<= 1) {
        uint32_t v = (tid >= off) ? psum[tid - off] : 0u;
        __syncthreads();
        psum[tid] += v;
        __syncthreads();
    }
    uint32_t above = tid ? psum[tid - 1] : 0u;
    if (psum[tid] >= PRE_NMS && above < PRE_NMS) {   // unique crossing chunk
        uint32_t c = above;
        int bin = base;
        for (int i = 15; i >= 0; --i) {
            c += hist[base + i];
            if (c >= PRE_NMS) { bin = base + i; break; }
        }
        thrbin = (uint32_t)bin;
    }
    __syncthreads();             // thrbin visible; hist dead below this line
    uint32_t tb = thrbin;

    // pass 2: compact candidates straight into the sort buffer (s aliases hist)
    for (int i = tid; i < NPER / 4; i += 1024) {
        float4 v = sc4[i];
        float cc[4] = {v.x, v.y, v.z, v.w};
#pragma unroll
        for (int c = 0; c < 4; ++c) {
            uint32_t k = fkey(cc[c]);
            if ((k >> 18) >= tb) {
                uint32_t pos = atomicAdd(&lcnt, 1u);
                if (pos < CAND_CAP) {
                    int e = 4 * i + c;                 // e = a*HWSZ + p
                    int a = e / HWSZ, p = e - a * HWSZ;
                    s[pos] = ((uint64_t)(~k) << 32) | (uint32_t)(p * A_NUM + a);
                }
            }
        }
    }
    __syncthreads();
    int m = (int)min(lcnt, (uint32_t)CAND_CAP);
    for (int i = m + tid; i < CAND_CAP; i += 1024) s[i] = ~0ull;
    __syncthreads();

    // bitonic sort 8192 x u64 (ascending; key = ~fkey<<32 | idx)
    for (unsigned k = 2; k <= CAND_CAP; k <<= 1) {
        for (unsigned j = k >> 1; j; j >>= 1) {
            for (unsigned p = tid; p < CAND_CAP / 2; p += 1024) {
                unsigned i = ((p & ~(j - 1)) << 1) | (p & (j - 1));
                unsigned ixj = i | j;
                uint64_t x = s[i], y = s[ixj];
                bool up = ((i & k) == 0);
                bool sw = up ? (x > y) : (x < y);
                if (sw) { s[i] = y; s[ixj] = x; }
            }
            __syncthreads();
        }
    }

    // decode top-6000
    float him = im_info[b * 3 + 0], wim = im_info[b * 3 + 1];
    float ymax = __fsub_rn(him, 1.0f), xmax = __fsub_rn(wim, 1.0f);
    for (int r0 = tid; r0 < PRE_NMS; r0 += 1024) {
        uint32_t idx = (uint32_t)s[r0];
        float4 bx = make_float4(0.f, 0.f, 0.f, 0.f);
        if (idx < NPER) {
            int a = idx % A_NUM;
            int p = idx / A_NUM;
            int wc = p % W_FEAT, hr = p / W_FEAT;
            float ax1 = ANC[a][0] + (float)(wc * 16);
            float ay1 = ANC[a][1] + (float)(hr * 16);
            float ax2 = ANC[a][2] + (float)(wc * 16);
            float ay2 = ANC[a][3] + (float)(hr * 16);
            const float* dp = deltas + (size_t)(b * 36 + a * 4) * HWSZ + p;
            float dx = dp[0], dy = dp[HWSZ], dw = dp[2 * HWSZ], dh = dp[3 * HWSZ];
            float ww = __fadd_rn(__fsub_rn(ax2, ax1), 1.0f);
            float hh = __fadd_rn(__fsub_rn(ay2, ay1), 1.0f);
            float cx = __fadd_rn(ax1, __fmul_rn(0.5f, ww));
            float cy = __fadd_rn(ay1, __fmul_rn(0.5f, hh));
            float pcx = __fadd_rn(__fmul_rn(dx, ww), cx);
            float pcy = __fadd_rn(__fmul_rn(dy, hh), cy);
            float ew = (float)exp((double)dw);
            float eh = (float)exp((double)dh);
            float pw = __fmul_rn(ew, ww);
            float ph = __fmul_rn(eh, hh);
            float x1 = __fsub_rn(pcx, __fmul_rn(0.5f, pw));
            float y1 = __fsub_rn(pcy, __fmul_rn(0.5f, ph));
            float x2 = __fadd_rn(pcx, __fmul_rn(0.5f, pw));
            float y2 = __fadd_rn(pcy, __fmul_rn(0.5f, ph));
            bx.x = fminf(fmaxf(x1, 0.0f), xmax);
            bx.y = fminf(fmaxf(y1, 0.0f), ymax);
            bx.z = fminf(fmaxf(x2, 0.0f), xmax);
            bx.w = fminf(fmaxf(y2, 0.0f), ymax);
        }
        boxes[(size_t)b * PRE_NMS + r0] = bx;
    }
}

// ---- K2: suppression bitmask for first NC candidates (64x64 wave tiles) -----
__global__ __launch_bounds__(256) void k_mask(const float4* __restrict__ boxes,
                                              uint64_t* __restrict__ masks,
                                              int NC, int NW, int T) {
    int b = blockIdx.y;
    int wv = threadIdx.x >> 6, lane = threadIdx.x & 63;
    int t = blockIdx.x * 4 + wv;
    if (t >= T) return;
    int ti = 0, rem = t;
    while (rem >= NW - ti) { rem -= NW - ti; ++ti; }   // upper-triangle map
    int tj = ti + rem;
    __shared__ float4 colb[4][64];
    __shared__ float  cola[4][64];
    const float4* bb = boxes + (size_t)b * PRE_NMS;
    int i = ti * 64 + lane;
    float4 c = bb[i];
    float ca = area_of(c);
    float4 q0 = bb[tj * 64 + lane];
    colb[wv][lane] = q0;
    cola[wv][lane] = area_of(q0);
    asm volatile("s_waitcnt lgkmcnt(0)" ::: "memory");  // single-wave LDS sync
    __builtin_amdgcn_wave_barrier();
    uint64_t m = 0;
    if (ti == tj) {            // diagonal: need j>i test (jj > lane)
#pragma unroll
        for (int jj = 0; jj < 64; ++jj) {
            bool hit = (jj > lane) && iou_gt(colb[wv][jj], cola[wv][jj], c, ca);
            m |= ((uint64_t)(hit ? 1u : 0u)) << jj;
        }
    } else {                   // off-diagonal: all j>i
#pragma unroll
        for (int jj = 0; jj < 64; ++jj) {
            bool hit = iou_gt(colb[wv][jj], cola[wv][jj], c, ca);
            m |= ((uint64_t)(hit ? 1u : 0u)) << jj;
        }
    }
    masks[((size_t)b * NW + tj) * NC + i] = m;
}

// kept-list register helpers (slot s holds kept[s*64+lane])
#define PROC(P)                                                                \
    do {                                                                       \
        float ca = area_of(P);                                                 \
        bool viol = false;                                                     \
        if (K > 0)   viol |= (lane       < K) & iou_gt(k0, a0, P, ca);         \
        if (K > 64)  viol |= (lane + 64  < K) & iou_gt(k1, a1, P, ca);         \
        if (K > 128) viol |= (lane + 128 < K) & iou_gt(k2, a2, P, ca);         \
        if (K > 192) viol |= (lane + 192 < K) & iou_gt(k3, a3, P, ca);         \
        if (K > 256) viol |= (lane + 256 < K) & iou_gt(k4, a4, P, ca);         \
        if (!__any((int)viol)) {                                               \
            int sl = K >> 6, tg = K & 63;                                      \
            if (lane == tg) {                                                  \
                switch (sl) {                                                  \
                case 0: k0 = P; a0 = ca; break;                                \
                case 1: k1 = P; a1 = ca; break;                                \
                case 2: k2 = P; a2 = ca; break;                                \
                case 3: k3 = P; a3 = ca; break;                                \
                default: k4 = P; a4 = ca; break;                               \
                }                                                              \
            }                                                                  \
            ++K;                                                               \
        }                                                                      \
    } while (0)

// one mask-walk step: consume ring reg RG (= row i), reload with row i+8
#define RSTEP(RG)                                                              \
    do {                                                                       \
        if (!fin && i < NC) {                                                  \
            bool mine = (lane == (i >> 6));                                    \
            bool sb = mine && ((sup >> (i & 63)) & 1ull);                      \
            if (!__any((int)sb)) {                                             \
                int sl = K >> 6, tg = K & 63;                                  \
                if (lane == tg) {                                              \
                    switch (sl) {                                              \
                    case 0: i0 = i; break;                                     \
                    case 1: i1 = i; break;                                     \
                    case 2: i2 = i; break;                                     \
                    case 3: i3 = i; break;                                     \
                    default: i4 = i; break;                                    \
                    }                                                          \
                }                                                              \
                if (lane < NW) sup |= RG;                                      \
                ++K;                                                           \
                if (K >= POST_NMS) fin = true;                                 \
            }                                                                  \
            int nx = i + 8; if (nx >= NC) nx = NC - 1;                         \
            RG = mrow[nx];                                                     \
            ++i;                                                               \
        }                                                                      \
    } while (0)

// ---- K3: greedy resolve, one wave per batch ---------------------------------
__global__ __launch_bounds__(64) void k_resolve(const float4* __restrict__ boxes,
                                                const uint64_t* __restrict__ masks,
                                                int NC, int NW,
                                                float* __restrict__ out) {
    int b = blockIdx.x, lane = threadIdx.x;
    const float4* bb = boxes + (size_t)b * PRE_NMS;
    int K = 0;
    int i0 = 0, i1 = 0, i2 = 0, i3 = 0, i4 = 0;
    bool fin = false;

    if (NC > 0) {
        const uint64_t* mrow =
            masks + ((size_t)b * NW + (lane < NW ? lane : NW - 1)) * NC;
        uint64_t sup = 0;
        uint64_t r0 = mrow[0], r1 = mrow[1], r2 = mrow[2], r3 = mrow[3];
        uint64_t r4 = mrow[4], r5 = mrow[5], r6 = mrow[6], r7 = mrow[7];
        int i = 0;
        while (i < NC && !fin) {
            RSTEP(r0); RSTEP(r1); RSTEP(r2); RSTEP(r3);
            RSTEP(r4); RSTEP(r5); RSTEP(r6); RSTEP(r7);
        }
    }

    // gather kept boxes into lane-cycled registers
    float4 k0, k1, k2, k3, k4;
    float a0, a1, a2, a3, a4;
    { int id = (lane       < K) ? i0 : 0; k0 = bb[id]; a0 = area_of(k0); }
    { int id = (lane + 64  < K) ? i1 : 0; k1 = bb[id]; a1 = area_of(k1); }
    { int id = (lane + 128 < K) ? i2 : 0; k2 = bb[id]; a2 = area_of(k2); }
    { int id = (lane + 192 < K) ? i3 : 0; k3 = bb[id]; a3 = area_of(k3); }
    { int id = (lane + 256 < K) ? i4 : 0; k4 = bb[id]; a4 = area_of(k4); }

    // fallback: continue exact greedy walk past NC if needed
    if (!fin && NC < PRE_NMS) {
        float4 p0 = bb[NC + 0], p1 = bb[NC + 1], p2 = bb[NC + 2], p3 = bb[NC + 3];
        bool done = false;
        for (int r = NC; r < PRE_NMS && !done; r += 4) {
            int n = r + 4;
            float4 n0 = bb[(n + 0 < PRE_NMS) ? n + 0 : PRE_NMS - 1];
            float4 n1 = bb[(n + 1 < PRE_NMS) ? n + 1 : PRE_NMS - 1];
            float4 n2 = bb[(n + 2 < PRE_NMS) ? n + 2 : PRE_NMS - 1];
            float4 n3 = bb[(n + 3 < PRE_NMS) ? n + 3 : PRE_NMS - 1];
            PROC(p0); if (K >= POST_NMS) done = true;
            if (!done) { PROC(p1); if (K >= POST_NMS) done = true; }
            if (!done) { PROC(p2); if (K >= POST_NMS) done = true; }
            if (!done) { PROC(p3); if (K >= POST_NMS) done = true; }
            p0 = n0; p1 = n1; p2 = n2; p3 = n3;
        }
    }

    // output kept[s*64+lane]
#pragma unroll
    for (int s = 0; s < 5; ++s) {
        int idx = s * 64 + lane;
        if (idx < POST_NMS) {
            float4 c;
            switch (s) {
            case 0: c = k0; break;
            case 1: c = k1; break;
            case 2: c = k2; break;
            case 3: c = k3; break;
            default: c = k4; break;
            }
            bool v = idx < K;
            float* o = out + (size_t)(b * POST_NMS + idx) * 5;
            o[0] = (float)b;
            o[1] = v ? c.x : 0.f;
            o[2] = v ? c.y : 0.f;
            o[3] = v ? c.z : 0.f;
            o[4] = v ? c.w : 0.f;
        }
    }
}

extern "C" void kernel_launch(void* const* d_in, const int* in_sizes, int n_in,
                              void* d_out, int out_size, void* d_ws, size_t ws_size,
                              hipStream_t stream) {
    const float* scores  = (const float*)d_in[0];
    const float* deltas  = (const float*)d_in[1];
    const float* im_info = (const float*)d_in[2];
    float* out = (float*)d_out;
    char* ws = (char*)d_ws;

    size_t boxBytes = (size_t)B_NUM * PRE_NMS * 16;           // 1.5 MB
    int NC = 0;
    const int ladder[4] = {4096, 3072, 2048, 1024};
    for (int li = 0; li < 4; ++li) {
        size_t mb = (size_t)B_NUM * (size_t)ladder[li] * (size_t)(ladder[li] / 64) * 8;
        if (boxBytes + mb <= ws_size) { NC = ladder[li]; break; }
    }
    int NW = NC / 64;

    float4*   boxes = (float4*)ws;
    uint64_t* masks = (uint64_t*)(ws + boxBytes);

    k_select<<<B_NUM, 1024, 0, stream>>>(scores, deltas, im_info, boxes);
    if (NC > 0) {
        int T = NW * (NW + 1) / 2;
        dim3 gm((T + 3) / 4, B_NUM);
        k_mask<<<gm, 256, 0, stream>>>(boxes, masks, NC, NW, T);
    }
    k_resolve<<<B_NUM, 64, 0, stream>>>(boxes, masks, NC, NW, out);
}

// Round 8
// 225.781 us; speedup vs baseline: 3.1076x; 1.2376x over previous
//
#include <hip/hip_runtime.h>
#include <cstdint>
#include <cmath>

#define HWSZ    15000      // H*W = 100*150
#define W_FEAT  150
#define A_NUM   9
#define NPER    135000     // A_NUM * HWSZ
#define B_NUM   16
#define PRE_NMS 6000
#define POST_NMS 300
#define NBINS   16384      // top-14-bit histogram
#define GCAP    2048       // per-group sort capacity

// 9 base anchors from generate_anchors(16,[0.5,1,2],[8,16,32]).
__device__ __constant__ float ANC[9][4] = {
    {-84.f,  -40.f,  99.f,  55.f},
    {-176.f, -88.f, 191.f, 103.f},
    {-360.f,-184.f, 375.f, 199.f},
    {-56.f,  -56.f,  71.f,  71.f},
    {-120.f,-120.f, 135.f, 135.f},
    {-248.f,-248.f, 263.f, 263.f},
    {-36.f,  -80.f,  51.f,  95.f},
    {-80.f, -168.f,  95.f, 183.f},
    {-168.f,-344.f, 183.f, 359.f}};

__device__ __forceinline__ uint32_t fkey(float s) {
    uint32_t u = __float_as_uint(s);
    return (u & 0x80000000u) ? ~u : (u | 0x80000000u);  // monotone key
}

// EXACT replacement for  __fdiv_rn(inter,den) > 0.7f  (see r6 derivation):
// m = midpoint(0.7f,next(0.7f)) = 0x1.666667p-1 (25 bits); m*(double)den exact.
__device__ __forceinline__ bool iou_gt(const float4& q, float qa,
                                       const float4& c, float ca) {
    float xx1 = fmaxf(q.x, c.x);
    float yy1 = fmaxf(q.y, c.y);
    float xx2 = fminf(q.z, c.z);
    float yy2 = fminf(q.w, c.w);
    float iw = fmaxf(0.0f, __fadd_rn(__fsub_rn(xx2, xx1), 1.0f));
    float ih = fmaxf(0.0f, __fadd_rn(__fsub_rn(yy2, yy1), 1.0f));
    float inter = __fmul_rn(iw, ih);
    float den = __fsub_rn(__fadd_rn(qa, ca), inter);
    return (double)inter >= 0x1.666667p-1 * (double)den;
}

__device__ __forceinline__ float area_of(const float4& c) {
    return __fmul_rn(__fadd_rn(__fsub_rn(c.z, c.x), 1.0f),
                     __fadd_rn(__fsub_rn(c.w, c.y), 1.0f));
}

// ---- K1: per-slice private histograms (no global atomics) -------------------
__global__ __launch_bounds__(1024) void k_hist(const float* __restrict__ scores,
                                               uint32_t* __restrict__ subhist) {
    __shared__ uint32_t hist[NBINS];          // 64KB
    int b = blockIdx.y, sx = blockIdx.x, S = gridDim.x, tid = threadIdx.x;
    for (int i = tid; i < NBINS; i += 1024) hist[i] = 0;
    __syncthreads();
    const float4* sc4 = (const float4*)(scores + (size_t)(b * 18 + 9) * HWSZ);
    int nf4 = NPER / 4;                       // 33750
    int per = (nf4 + S - 1) / S;
    int lo = sx * per, hi = min(lo + per, nf4);
    for (int i = lo + tid; i < hi; i += 1024) {
        float4 v = sc4[i];
        atomicAdd(&hist[fkey(v.x) >> 18], 1u);
        atomicAdd(&hist[fkey(v.y) >> 18], 1u);
        atomicAdd(&hist[fkey(v.z) >> 18], 1u);
        atomicAdd(&hist[fkey(v.w) >> 18], 1u);
    }
    __syncthreads();
    uint32_t* out = subhist + ((size_t)b * S + sx) * NBINS;
    for (int i = tid; i < NBINS; i += 1024) out[i] = hist[i];
}

// ---- K2: per-bin exclusive-from-top cum table + group base offsets ----------
__global__ __launch_bounds__(1024) void k_scan(const uint32_t* __restrict__ subhist,
                                               int S, uint32_t* __restrict__ scum,
                                               uint32_t* __restrict__ gbase) {
    __shared__ uint32_t tl[NBINS];            // 64KB summed hist
    __shared__ uint32_t psum[1024];
    __shared__ uint32_t gb[8];
    int b = blockIdx.x, tid = threadIdx.x;
    for (int i = tid; i < NBINS; i += 1024) {
        uint32_t t = 0;
        for (int u = 0; u < S; ++u) t += subhist[((size_t)b * S + u) * NBINS + i];
        tl[i] = t;
    }
    if (tid < 8) gb[tid] = 0xFFFFFFFFu;
    __syncthreads();
    int base = NBINS - 16 * (tid + 1);        // chunk tid: descending bins
    uint32_t csum = 0;
#pragma unroll
    for (int i = 0; i < 16; ++i) csum += tl[base + i];
    psum[tid] = csum;
    __syncthreads();
    for (int off = 1; off < 1024; off <<= 1) {
        uint32_t v = (tid >= off) ? psum[tid - off] : 0u;
        __syncthreads();
        psum[tid] += v;
        __syncthreads();
    }
    uint32_t c = tid ? psum[tid - 1] : 0u;    // exclusive cum before this chunk
    for (int i = 15; i >= 0; --i) {           // bins descending within chunk
        uint32_t t = tl[base + i];
        scum[(size_t)b * NBINS + base + i] = c;
        if (t && c < PRE_NMS) atomicMin(&gb[c >> 10], c);
        c += t;
    }
    __syncthreads();
    if (tid < 8) gbase[b * 8 + tid] = gb[tid];
}

// ---- K3: per-group compact + bitonic(2048) + decode -------------------------
__global__ __launch_bounds__(1024) void k_group(
        const float* __restrict__ scores, const float* __restrict__ deltas,
        const float* __restrict__ im_info, const uint32_t* __restrict__ scum,
        const uint32_t* __restrict__ gbase, float4* __restrict__ boxes) {
    __shared__ uint32_t sl[NBINS];            // 64KB scum cache
    __shared__ uint64_t s[GCAP];              // 16KB sort buffer
    __shared__ uint32_t lcnt;
    int b = blockIdx.y, g = blockIdx.x, tid = threadIdx.x;
    uint32_t base = gbase[b * 8 + g];
    if (base == 0xFFFFFFFFu) return;          // empty group (uniform)
    for (int i = tid; i < NBINS; i += 1024) sl[i] = scum[(size_t)b * NBINS + i];
    for (int i = tid; i < GCAP; i += 1024) s[i] = ~0ull;
    if (tid == 0) lcnt = 0;
    __syncthreads();
    uint32_t glo = (uint32_t)g << 10;
    uint32_t ghi = min(glo + 1024u, (uint32_t)PRE_NMS);
    const float4* sc4 = (const float4*)(scores + (size_t)(b * 18 + 9) * HWSZ);
    for (int i = tid; i < NPER / 4; i += 1024) {
        float4 v = sc4[i];
        float cc[4] = {v.x, v.y, v.z, v.w};
#pragma unroll
        for (int c = 0; c < 4; ++c) {
            uint32_t k = fkey(cc[c]);
            uint32_t sc = sl[k >> 18];
            if (sc >= glo && sc < ghi) {      // bin belongs to group g, in top-6000
                uint32_t pos = atomicAdd(&lcnt, 1u);
                if (pos < GCAP) {
                    int e = 4 * i + c;        // e = a*HWSZ + p
                    int a = e / HWSZ, p = e - a * HWSZ;
                    s[pos] = ((uint64_t)(~k) << 32) | (uint32_t)(p * A_NUM + a);
                }
            }
        }
    }
    __syncthreads();
    int cnt = (int)min(lcnt, (uint32_t)GCAP);
    // bitonic sort 2048 (1024 threads = 1 pair each)
    for (unsigned k = 2; k <= GCAP; k <<= 1) {
        for (unsigned j = k >> 1; j; j >>= 1) {
            unsigned p = tid;
            unsigned i = ((p & ~(j - 1)) << 1) | (p & (j - 1));
            unsigned ixj = i | j;
            uint64_t x = s[i], y = s[ixj];
            bool up = ((i & k) == 0);
            if (up ? (x > y) : (x < y)) { s[i] = y; s[ixj] = x; }
            __syncthreads();
        }
    }
    // decode ranks [base, base+cnt) ∩ [0, PRE_NMS)
    float him = im_info[b * 3 + 0], wim = im_info[b * 3 + 1];
    float ymax = __fsub_rn(him, 1.0f), xmax = __fsub_rn(wim, 1.0f);
    for (int r = tid; r < GCAP; r += 1024) {
        uint32_t P = base + (uint32_t)r;
        uint32_t idx = (uint32_t)s[r];
        if (r < cnt && P < PRE_NMS && idx < NPER) {
            int a = idx % A_NUM;
            int p = idx / A_NUM;
            int wc = p % W_FEAT, hr = p / W_FEAT;
            float ax1 = ANC[a][0] + (float)(wc * 16);
            float ay1 = ANC[a][1] + (float)(hr * 16);
            float ax2 = ANC[a][2] + (float)(wc * 16);
            float ay2 = ANC[a][3] + (float)(hr * 16);
            const float* dp = deltas + (size_t)(b * 36 + a * 4) * HWSZ + p;
            float dx = dp[0], dy = dp[HWSZ], dw = dp[2 * HWSZ], dh = dp[3 * HWSZ];
            float ww = __fadd_rn(__fsub_rn(ax2, ax1), 1.0f);
            float hh = __fadd_rn(__fsub_rn(ay2, ay1), 1.0f);
            float cx = __fadd_rn(ax1, __fmul_rn(0.5f, ww));
            float cy = __fadd_rn(ay1, __fmul_rn(0.5f, hh));
            float pcx = __fadd_rn(__fmul_rn(dx, ww), cx);
            float pcy = __fadd_rn(__fmul_rn(dy, hh), cy);
            float ew = (float)exp((double)dw);
            float eh = (float)exp((double)dh);
            float pw = __fmul_rn(ew, ww);
            float ph = __fmul_rn(eh, hh);
            float x1 = __fsub_rn(pcx, __fmul_rn(0.5f, pw));
            float y1 = __fsub_rn(pcy, __fmul_rn(0.5f, ph));
            float x2 = __fadd_rn(pcx, __fmul_rn(0.5f, pw));
            float y2 = __fadd_rn(pcy, __fmul_rn(0.5f, ph));
            float4 bx;
            bx.x = fminf(fmaxf(x1, 0.0f), xmax);
            bx.y = fminf(fmaxf(y1, 0.0f), ymax);
            bx.z = fminf(fmaxf(x2, 0.0f), xmax);
            bx.w = fminf(fmaxf(y2, 0.0f), ymax);
            boxes[(size_t)b * PRE_NMS + P] = bx;
        }
    }
}

// ---- K4: suppression bitmask for first NC candidates (64x64 wave tiles) -----
__global__ __launch_bounds__(256) void k_mask(const float4* __restrict__ boxes,
                                              uint64_t* __restrict__ masks,
                                              int NC, int NW, int T) {
    int b = blockIdx.y;
    int wv = threadIdx.x >> 6, lane = threadIdx.x & 63;
    int t = blockIdx.x * 4 + wv;
    if (t >= T) return;
    int ti = 0, rem = t;
    while (rem >= NW - ti) { rem -= NW - ti; ++ti; }   // upper-triangle map
    int tj = ti + rem;
    __shared__ float4 colb[4][64];
    __shared__ float  cola[4][64];
    const float4* bb = boxes + (size_t)b * PRE_NMS;
    int i = ti * 64 + lane;
    float4 c = bb[i];
    float ca = area_of(c);
    float4 q0 = bb[tj * 64 + lane];
    colb[wv][lane] = q0;
    cola[wv][lane] = area_of(q0);
    asm volatile("s_waitcnt lgkmcnt(0)" ::: "memory");  // single-wave LDS sync
    __builtin_amdgcn_wave_barrier();
    uint64_t m = 0;
    if (ti == tj) {
#pragma unroll
        for (int jj = 0; jj < 64; ++jj) {
            bool hit = (jj > lane) && iou_gt(colb[wv][jj], cola[wv][jj], c, ca);
            m |= ((uint64_t)(hit ? 1u : 0u)) << jj;
        }
    } else {
#pragma unroll
        for (int jj = 0; jj < 64; ++jj) {
            bool hit = iou_gt(colb[wv][jj], cola[wv][jj], c, ca);
            m |= ((uint64_t)(hit ? 1u : 0u)) << jj;
        }
    }
    masks[((size_t)b * NW + tj) * NC + i] = m;
}

// kept-list register helpers (slot s holds kept[s*64+lane])
#define PROC(P)                                                                \
    do {                                                                       \
        float ca = area_of(P);                                                 \
        bool viol = false;                                                     \
        if (K > 0)   viol |= (lane       < K) & iou_gt(k0, a0, P, ca);         \
        if (K > 64)  viol |= (lane + 64  < K) & iou_gt(k1, a1, P, ca);         \
        if (K > 128) viol |= (lane + 128 < K) & iou_gt(k2, a2, P, ca);         \
        if (K > 192) viol |= (lane + 192 < K) & iou_gt(k3, a3, P, ca);         \
        if (K > 256) viol |= (lane + 256 < K) & iou_gt(k4, a4, P, ca);         \
        if (!__any((int)viol)) {                                               \
            int sl = K >> 6, tg = K & 63;                                      \
            if (lane == tg) {                                                  \
                switch (sl) {                                                  \
                case 0: k0 = P; a0 = ca; break;                                \
                case 1: k1 = P; a1 = ca; break;                                \
                case 2: k2 = P; a2 = ca; break;                                \
                case 3: k3 = P; a3 = ca; break;                                \
                default: k4 = P; a4 = ca; break;                               \
                }                                                              \
            }                                                                  \
            ++K;                                                               \
        }                                                                      \
    } while (0)

// one mask-walk step: consume ring reg RG (= row i), reload with row i+8
#define RSTEP(RG)                                                              \
    do {                                                                       \
        if (!fin && i < NC) {                                                  \
            bool mine = (lane == (i >> 6));                                    \
            bool sb = mine && ((sup >> (i & 63)) & 1ull);                      \
            if (!__any((int)sb)) {                                             \
                int sl = K >> 6, tg = K & 63;                                  \
                if (lane == tg) {                                              \
                    switch (sl) {                                              \
                    case 0: i0 = i; break;                                     \
                    case 1: i1 = i; break;                                     \
                    case 2: i2 = i; break;                                     \
                    case 3: i3 = i; break;                                     \
                    default: i4 = i; break;                                    \
                    }                                                          \
                }                                                              \
                if (lane < NW) sup |= RG;                                      \
                ++K;                                                           \
                if (K >= POST_NMS) fin = true;                                 \
            }                                                                  \
            int nx = i + 8; if (nx >= NC) nx = NC - 1;                         \
            RG = mrow[nx];                                                     \
            ++i;                                                               \
        }                                                                      \
    } while (0)

// ---- K5: greedy resolve, one wave per batch ---------------------------------
__global__ __launch_bounds__(64) void k_resolve(const float4* __restrict__ boxes,
                                                const uint64_t* __restrict__ masks,
                                                int NC, int NW,
                                                float* __restrict__ out) {
    int b = blockIdx.x, lane = threadIdx.x;
    const float4* bb = boxes + (size_t)b * PRE_NMS;
    int K = 0;
    int i0 = 0, i1 = 0, i2 = 0, i3 = 0, i4 = 0;
    bool fin = false;

    if (NC > 0) {
        const uint64_t* mrow =
            masks + ((size_t)b * NW + (lane < NW ? lane : NW - 1)) * NC;
        uint64_t sup = 0;
        uint64_t r0 = mrow[0], r1 = mrow[1], r2 = mrow[2], r3 = mrow[3];
        uint64_t r4 = mrow[4], r5 = mrow[5], r6 = mrow[6], r7 = mrow[7];
        int i = 0;
        while (i < NC && !fin) {
            RSTEP(r0); RSTEP(r1); RSTEP(r2); RSTEP(r3);
            RSTEP(r4); RSTEP(r5); RSTEP(r6); RSTEP(r7);
        }
    }

    // gather kept boxes into lane-cycled registers
    float4 k0, k1, k2, k3, k4;
    float a0, a1, a2, a3, a4;
    { int id = (lane       < K) ? i0 : 0; k0 = bb[id]; a0 = area_of(k0); }
    { int id = (lane + 64  < K) ? i1 : 0; k1 = bb[id]; a1 = area_of(k1); }
    { int id = (lane + 128 < K) ? i2 : 0; k2 = bb[id]; a2 = area_of(k2); }
    { int id = (lane + 192 < K) ? i3 : 0; k3 = bb[id]; a3 = area_of(k3); }
    { int id = (lane + 256 < K) ? i4 : 0; k4 = bb[id]; a4 = area_of(k4); }

    // fallback: continue exact greedy walk past NC if needed
    if (!fin && NC < PRE_NMS) {
        float4 p0 = bb[NC + 0], p1 = bb[NC + 1], p2 = bb[NC + 2], p3 = bb[NC + 3];
        bool done = false;
        for (int r = NC; r < PRE_NMS && !done; r += 4) {
            int n = r + 4;
            float4 n0 = bb[(n + 0 < PRE_NMS) ? n + 0 : PRE_NMS - 1];
            float4 n1 = bb[(n + 1 < PRE_NMS) ? n + 1 : PRE_NMS - 1];
            float4 n2 = bb[(n + 2 < PRE_NMS) ? n + 2 : PRE_NMS - 1];
            float4 n3 = bb[(n + 3 < PRE_NMS) ? n + 3 : PRE_NMS - 1];
            PROC(p0); if (K >= POST_NMS) done = true;
            if (!done) { PROC(p1); if (K >= POST_NMS) done = true; }
            if (!done) { PROC(p2); if (K >= POST_NMS) done = true; }
            if (!done) { PROC(p3); if (K >= POST_NMS) done = true; }
            p0 = n0; p1 = n1; p2 = n2; p3 = n3;
        }
    }

    // output kept[s*64+lane]
#pragma unroll
    for (int s = 0; s < 5; ++s) {
        int idx = s * 64 + lane;
        if (idx < POST_NMS) {
            float4 c;
            switch (s) {
            case 0: c = k0; break;
            case 1: c = k1; break;
            case 2: c = k2; break;
            case 3: c = k3; break;
            default: c = k4; break;
            }
            bool v = idx < K;
            float* o = out + (size_t)(b * POST_NMS + idx) * 5;
            o[0] = (float)b;
            o[1] = v ? c.x : 0.f;
            o[2] = v ? c.y : 0.f;
            o[3] = v ? c.z : 0.f;
            o[4] = v ? c.w : 0.f;
        }
    }
}

extern "C" void kernel_launch(void* const* d_in, const int* in_sizes, int n_in,
                              void* d_out, int out_size, void* d_ws, size_t ws_size,
                              hipStream_t stream) {
    const float* scores  = (const float*)d_in[0];
    const float* deltas  = (const float*)d_in[1];
    const float* im_info = (const float*)d_in[2];
    float* out = (float*)d_out;
    char* ws = (char*)d_ws;

    // layout: boxes(1.5MB) | scum(1MB) | gbase(4KB pad) | subhist(S MB) | masks
    const size_t boxB  = (size_t)B_NUM * PRE_NMS * 16;        // 1,536,000
    const size_t scumB = (size_t)B_NUM * NBINS * 4;           // 1,048,576
    const size_t fixedB = boxB + scumB + 4096;                // 2,588,672
    int NC = 0, S = 1;
    const int lad[4] = {4096, 3072, 2048, 1024};
    for (int li = 0; li < 4 && !NC; ++li) {
        size_t mb = 2ull * lad[li] * lad[li];                 // 16*NW*NC*8 = 2*NC^2
        if (fixedB + 1048576ull + mb <= ws_size) {
            NC = lad[li];
            for (int ss = 8; ss >= 1; ss >>= 1)
                if (fixedB + (size_t)ss * 1048576ull + mb <= ws_size) { S = ss; break; }
        }
    }
    if (!NC) { NC = 1024; S = 1; }
    int NW = NC / 64;

    float4*   boxes   = (float4*)ws;
    uint32_t* scum    = (uint32_t*)(ws + boxB);
    uint32_t* gbase   = (uint32_t*)(ws + boxB + scumB);
    uint32_t* subhist = (uint32_t*)(ws + fixedB);
    uint64_t* masks   = (uint64_t*)(ws + fixedB + (size_t)S * 1048576ull);

    dim3 gh(S, B_NUM);
    k_hist<<<gh, 1024, 0, stream>>>(scores, subhist);
    k_scan<<<B_NUM, 1024, 0, stream>>>(subhist, S, scum, gbase);
    dim3 gg(6, B_NUM);
    k_group<<<gg, 1024, 0, stream>>>(scores, deltas, im_info, scum, gbase, boxes);
    int T = NW * (NW + 1) / 2;
    dim3 gm((T + 3) / 4, B_NUM);
    k_mask<<<gm, 256, 0, stream>>>(boxes, masks, NC, NW, T);
    k_resolve<<<B_NUM, 64, 0, stream>>>(boxes, masks, NC, NW, out);
}

// Round 9
// 170.675 us; speedup vs baseline: 4.1109x; 1.3229x over previous
//
#include <hip/hip_runtime.h>
#include <cstdint>
#include <cmath>

#define HWSZ    15000      // H*W = 100*150
#define W_FEAT  150
#define A_NUM   9
#define NPER    135000     // A_NUM * HWSZ
#define B_NUM   16
#define PRE_NMS 6000
#define POST_NMS 300
#define NBINS   16384      // top-14-bit histogram
#define GCAP    2048       // per-group sort capacity

// 9 base anchors from generate_anchors(16,[0.5,1,2],[8,16,32]).
__device__ __constant__ float ANC[9][4] = {
    {-84.f,  -40.f,  99.f,  55.f},
    {-176.f, -88.f, 191.f, 103.f},
    {-360.f,-184.f, 375.f, 199.f},
    {-56.f,  -56.f,  71.f,  71.f},
    {-120.f,-120.f, 135.f, 135.f},
    {-248.f,-248.f, 263.f, 263.f},
    {-36.f,  -80.f,  51.f,  95.f},
    {-80.f, -168.f,  95.f, 183.f},
    {-168.f,-344.f, 183.f, 359.f}};

__device__ __forceinline__ uint32_t fkey(float s) {
    uint32_t u = __float_as_uint(s);
    return (u & 0x80000000u) ? ~u : (u | 0x80000000u);  // monotone key
}

// EXACT replacement for  __fdiv_rn(inter,den) > 0.7f  (see r6 derivation):
// m = midpoint(0.7f,next(0.7f)) = 0x1.666667p-1 (25 bits); m*(double)den exact.
__device__ __forceinline__ bool iou_gt(const float4& q, float qa,
                                       const float4& c, float ca) {
    float xx1 = fmaxf(q.x, c.x);
    float yy1 = fmaxf(q.y, c.y);
    float xx2 = fminf(q.z, c.z);
    float yy2 = fminf(q.w, c.w);
    float iw = fmaxf(0.0f, __fadd_rn(__fsub_rn(xx2, xx1), 1.0f));
    float ih = fmaxf(0.0f, __fadd_rn(__fsub_rn(yy2, yy1), 1.0f));
    float inter = __fmul_rn(iw, ih);
    float den = __fsub_rn(__fadd_rn(qa, ca), inter);
    return (double)inter >= 0x1.666667p-1 * (double)den;
}

__device__ __forceinline__ float area_of(const float4& c) {
    return __fmul_rn(__fadd_rn(__fsub_rn(c.z, c.x), 1.0f),
                     __fadd_rn(__fsub_rn(c.w, c.y), 1.0f));
}

// ---- K1: per-slice private histograms (no global atomics) -------------------
__global__ __launch_bounds__(1024) void k_hist(const float* __restrict__ scores,
                                               uint32_t* __restrict__ subhist) {
    __shared__ uint32_t hist[NBINS];          // 64KB
    int b = blockIdx.y, sx = blockIdx.x, S = gridDim.x, tid = threadIdx.x;
    for (int i = tid; i < NBINS; i += 1024) hist[i] = 0;
    __syncthreads();
    const float4* sc4 = (const float4*)(scores + (size_t)(b * 18 + 9) * HWSZ);
    int nf4 = NPER / 4;                       // 33750
    int per = (nf4 + S - 1) / S;
    int lo = sx * per, hi = min(lo + per, nf4);
    for (int i = lo + tid; i < hi; i += 1024) {
        float4 v = sc4[i];
        atomicAdd(&hist[fkey(v.x) >> 18], 1u);
        atomicAdd(&hist[fkey(v.y) >> 18], 1u);
        atomicAdd(&hist[fkey(v.z) >> 18], 1u);
        atomicAdd(&hist[fkey(v.w) >> 18], 1u);
    }
    __syncthreads();
    uint32_t* out = subhist + ((size_t)b * S + sx) * NBINS;
    for (int i = tid; i < NBINS; i += 1024) out[i] = hist[i];
}

// ---- K2: per-bin exclusive-from-top cum table + group base offsets ----------
__global__ __launch_bounds__(1024) void k_scan(const uint32_t* __restrict__ subhist,
                                               int S, uint32_t* __restrict__ scum,
                                               uint32_t* __restrict__ gbase) {
    __shared__ uint32_t tl[NBINS];            // 64KB summed hist
    __shared__ uint32_t psum[1024];
    __shared__ uint32_t gb[8];
    int b = blockIdx.x, tid = threadIdx.x;
    for (int i = tid; i < NBINS; i += 1024) {
        uint32_t t = 0;
        for (int u = 0; u < S; ++u) t += subhist[((size_t)b * S + u) * NBINS + i];
        tl[i] = t;
    }
    if (tid < 8) gb[tid] = 0xFFFFFFFFu;
    __syncthreads();
    int base = NBINS - 16 * (tid + 1);        // chunk tid: descending bins
    uint32_t csum = 0;
#pragma unroll
    for (int i = 0; i < 16; ++i) csum += tl[base + i];
    psum[tid] = csum;
    __syncthreads();
    for (int off = 1; off < 1024; off <<= 1) {
        uint32_t v = (tid >= off) ? psum[tid - off] : 0u;
        __syncthreads();
        psum[tid] += v;
        __syncthreads();
    }
    uint32_t c = tid ? psum[tid - 1] : 0u;    // exclusive cum before this chunk
    for (int i = 15; i >= 0; --i) {           // bins descending within chunk
        uint32_t t = tl[base + i];
        scum[(size_t)b * NBINS + base + i] = c;
        if (t && c < PRE_NMS) atomicMin(&gb[c >> 10], c);
        c += t;
    }
    __syncthreads();
    if (tid < 8) gbase[b * 8 + tid] = gb[tid];
}

// ---- K3: per-group compact + bitonic(2048) + decode -------------------------
__global__ __launch_bounds__(1024) void k_group(
        const float* __restrict__ scores, const float* __restrict__ deltas,
        const float* __restrict__ im_info, const uint32_t* __restrict__ scum,
        const uint32_t* __restrict__ gbase, float4* __restrict__ boxes) {
    __shared__ uint32_t sl[NBINS];            // 64KB scum cache
    __shared__ uint64_t s[GCAP];              // 16KB sort buffer
    __shared__ uint32_t lcnt;
    int b = blockIdx.y, g = blockIdx.x, tid = threadIdx.x;
    uint32_t base = gbase[b * 8 + g];
    if (base == 0xFFFFFFFFu) return;          // empty group (uniform)
    for (int i = tid; i < NBINS; i += 1024) sl[i] = scum[(size_t)b * NBINS + i];
    for (int i = tid; i < GCAP; i += 1024) s[i] = ~0ull;
    if (tid == 0) lcnt = 0;
    __syncthreads();
    uint32_t glo = (uint32_t)g << 10;
    uint32_t ghi = min(glo + 1024u, (uint32_t)PRE_NMS);
    const float4* sc4 = (const float4*)(scores + (size_t)(b * 18 + 9) * HWSZ);
    for (int i = tid; i < NPER / 4; i += 1024) {
        float4 v = sc4[i];
        float cc[4] = {v.x, v.y, v.z, v.w};
#pragma unroll
        for (int c = 0; c < 4; ++c) {
            uint32_t k = fkey(cc[c]);
            uint32_t sc = sl[k >> 18];
            if (sc >= glo && sc < ghi) {      // bin belongs to group g, in top-6000
                uint32_t pos = atomicAdd(&lcnt, 1u);
                if (pos < GCAP) {
                    int e = 4 * i + c;        // e = a*HWSZ + p
                    int a = e / HWSZ, p = e - a * HWSZ;
                    s[pos] = ((uint64_t)(~k) << 32) | (uint32_t)(p * A_NUM + a);
                }
            }
        }
    }
    __syncthreads();
    int cnt = (int)min(lcnt, (uint32_t)GCAP);
    // bitonic sort 2048 (1024 threads = 1 pair each)
    for (unsigned k = 2; k <= GCAP; k <<= 1) {
        for (unsigned j = k >> 1; j; j >>= 1) {
            unsigned p = tid;
            unsigned i = ((p & ~(j - 1)) << 1) | (p & (j - 1));
            unsigned ixj = i | j;
            uint64_t x = s[i], y = s[ixj];
            bool up = ((i & k) == 0);
            if (up ? (x > y) : (x < y)) { s[i] = y; s[ixj] = x; }
            __syncthreads();
        }
    }
    // decode ranks [base, base+cnt) ∩ [0, PRE_NMS)
    float him = im_info[b * 3 + 0], wim = im_info[b * 3 + 1];
    float ymax = __fsub_rn(him, 1.0f), xmax = __fsub_rn(wim, 1.0f);
    for (int r = tid; r < GCAP; r += 1024) {
        uint32_t P = base + (uint32_t)r;
        uint32_t idx = (uint32_t)s[r];
        if (r < cnt && P < PRE_NMS && idx < NPER) {
            int a = idx % A_NUM;
            int p = idx / A_NUM;
            int wc = p % W_FEAT, hr = p / W_FEAT;
            float ax1 = ANC[a][0] + (float)(wc * 16);
            float ay1 = ANC[a][1] + (float)(hr * 16);
            float ax2 = ANC[a][2] + (float)(wc * 16);
            float ay2 = ANC[a][3] + (float)(hr * 16);
            const float* dp = deltas + (size_t)(b * 36 + a * 4) * HWSZ + p;
            float dx = dp[0], dy = dp[HWSZ], dw = dp[2 * HWSZ], dh = dp[3 * HWSZ];
            float ww = __fadd_rn(__fsub_rn(ax2, ax1), 1.0f);
            float hh = __fadd_rn(__fsub_rn(ay2, ay1), 1.0f);
            float cx = __fadd_rn(ax1, __fmul_rn(0.5f, ww));
            float cy = __fadd_rn(ay1, __fmul_rn(0.5f, hh));
            float pcx = __fadd_rn(__fmul_rn(dx, ww), cx);
            float pcy = __fadd_rn(__fmul_rn(dy, hh), cy);
            float ew = (float)exp((double)dw);
            float eh = (float)exp((double)dh);
            float pw = __fmul_rn(ew, ww);
            float ph = __fmul_rn(eh, hh);
            float x1 = __fsub_rn(pcx, __fmul_rn(0.5f, pw));
            float y1 = __fsub_rn(pcy, __fmul_rn(0.5f, ph));
            float x2 = __fadd_rn(pcx, __fmul_rn(0.5f, pw));
            float y2 = __fadd_rn(pcy, __fmul_rn(0.5f, ph));
            float4 bx;
            bx.x = fminf(fmaxf(x1, 0.0f), xmax);
            bx.y = fminf(fmaxf(y1, 0.0f), ymax);
            bx.z = fminf(fmaxf(x2, 0.0f), xmax);
            bx.w = fminf(fmaxf(y2, 0.0f), ymax);
            boxes[(size_t)b * PRE_NMS + P] = bx;
        }
    }
}

// ---- K4: suppression bitmask for first NC candidates (64x64 wave tiles) -----
__global__ __launch_bounds__(256) void k_mask(const float4* __restrict__ boxes,
                                              uint64_t* __restrict__ masks,
                                              int NC, int NW, int T) {
    int b = blockIdx.y;
    int wv = threadIdx.x >> 6, lane = threadIdx.x & 63;
    int t = blockIdx.x * 4 + wv;
    if (t >= T) return;
    int ti = 0, rem = t;
    while (rem >= NW - ti) { rem -= NW - ti; ++ti; }   // upper-triangle map
    int tj = ti + rem;
    __shared__ float4 colb[4][64];
    __shared__ float  cola[4][64];
    const float4* bb = boxes + (size_t)b * PRE_NMS;
    int i = ti * 64 + lane;
    float4 c = bb[i];
    float ca = area_of(c);
    float4 q0 = bb[tj * 64 + lane];
    colb[wv][lane] = q0;
    cola[wv][lane] = area_of(q0);
    asm volatile("s_waitcnt lgkmcnt(0)" ::: "memory");  // single-wave LDS sync
    __builtin_amdgcn_wave_barrier();
    uint64_t m = 0;
    if (ti == tj) {
#pragma unroll
        for (int jj = 0; jj < 64; ++jj) {
            bool hit = (jj > lane) && iou_gt(colb[wv][jj], cola[wv][jj], c, ca);
            m |= ((uint64_t)(hit ? 1u : 0u)) << jj;
        }
    } else {
#pragma unroll
        for (int jj = 0; jj < 64; ++jj) {
            bool hit = iou_gt(colb[wv][jj], cola[wv][jj], c, ca);
            m |= ((uint64_t)(hit ? 1u : 0u)) << jj;
        }
    }
    masks[((size_t)b * NW + tj) * NC + i] = m;
}

// kept-list register helpers (slot s holds kept[s*64+lane])
#define PROC(P)                                                                \
    do {                                                                       \
        float ca = area_of(P);                                                 \
        bool viol = false;                                                     \
        if (K > 0)   viol |= (lane       < K) & iou_gt(k0, a0, P, ca);         \
        if (K > 64)  viol |= (lane + 64  < K) & iou_gt(k1, a1, P, ca);         \
        if (K > 128) viol |= (lane + 128 < K) & iou_gt(k2, a2, P, ca);         \
        if (K > 192) viol |= (lane + 192 < K) & iou_gt(k3, a3, P, ca);         \
        if (K > 256) viol |= (lane + 256 < K) & iou_gt(k4, a4, P, ca);         \
        if (!__any((int)viol)) {                                               \
            int sl = K >> 6, tg = K & 63;                                      \
            if (lane == tg) {                                                  \
                switch (sl) {                                                  \
                case 0: k0 = P; a0 = ca; break;                                \
                case 1: k1 = P; a1 = ca; break;                                \
                case 2: k2 = P; a2 = ca; break;                                \
                case 3: k3 = P; a3 = ca; break;                                \
                default: k4 = P; a4 = ca; break;                               \
                }                                                              \
            }                                                                  \
            ++K;                                                               \
        }                                                                      \
    } while (0)

// one mask-walk step: consume ring reg RG (= row i), reload with row i+8
#define RSTEP(RG)                                                              \
    do {                                                                       \
        if (!fin && i < NC) {                                                  \
            bool mine = (lane == (i >> 6));                                    \
            bool sb = mine && ((sup >> (i & 63)) & 1ull);                      \
            if (!__any((int)sb)) {                                             \
                int sl = K >> 6, tg = K & 63;                                  \
                if (lane == tg) {                                              \
                    switch (sl) {                                              \
                    case 0: i0 = i; break;                                     \
                    case 1: i1 = i; break;                                     \
                    case 2: i2 = i; break;                                     \
                    case 3: i3 = i; break;                                     \
                    default: i4 = i; break;                                    \
                    }                                                          \
                }                                                              \
                if (lane < NW) sup |= RG;                                      \
                ++K;                                                           \
                if (K >= POST_NMS) fin = true;                                 \
            }                                                                  \
            int nx = i + 8; if (nx >= NC) nx = NC - 1;                         \
            RG = mrow[nx];                                                     \
            ++i;                                                               \
        }                                                                      \
    } while (0)

// ---- K5: greedy resolve, one wave per batch ---------------------------------
__global__ __launch_bounds__(64) void k_resolve(const float4* __restrict__ boxes,
                                                const uint64_t* __restrict__ masks,
                                                int NC, int NW,
                                                float* __restrict__ out) {
    int b = blockIdx.x, lane = threadIdx.x;
    const float4* bb = boxes + (size_t)b * PRE_NMS;
    int K = 0;
    int i0 = 0, i1 = 0, i2 = 0, i3 = 0, i4 = 0;
    bool fin = false;

    if (NC > 0) {
        const uint64_t* mrow =
            masks + ((size_t)b * NW + (lane < NW ? lane : NW - 1)) * NC;
        uint64_t sup = 0;
        uint64_t r0 = mrow[0], r1 = mrow[1], r2 = mrow[2], r3 = mrow[3];
        uint64_t r4 = mrow[4], r5 = mrow[5], r6 = mrow[6], r7 = mrow[7];
        int i = 0;
        while (i < NC && !fin) {
            RSTEP(r0); RSTEP(r1); RSTEP(r2); RSTEP(r3);
            RSTEP(r4); RSTEP(r5); RSTEP(r6); RSTEP(r7);
        }
    }

    // gather kept boxes into lane-cycled registers
    float4 k0, k1, k2, k3, k4;
    float a0, a1, a2, a3, a4;
    { int id = (lane       < K) ? i0 : 0; k0 = bb[id]; a0 = area_of(k0); }
    { int id = (lane + 64  < K) ? i1 : 0; k1 = bb[id]; a1 = area_of(k1); }
    { int id = (lane + 128 < K) ? i2 : 0; k2 = bb[id]; a2 = area_of(k2); }
    { int id = (lane + 192 < K) ? i3 : 0; k3 = bb[id]; a3 = area_of(k3); }
    { int id = (lane + 256 < K) ? i4 : 0; k4 = bb[id]; a4 = area_of(k4); }

    // fallback: continue exact greedy walk past NC if needed
    if (!fin && NC < PRE_NMS) {
        float4 p0 = bb[NC + 0], p1 = bb[NC + 1], p2 = bb[NC + 2], p3 = bb[NC + 3];
        bool done = false;
        for (int r = NC; r < PRE_NMS && !done; r += 4) {
            int n = r + 4;
            float4 n0 = bb[(n + 0 < PRE_NMS) ? n + 0 : PRE_NMS - 1];
            float4 n1 = bb[(n + 1 < PRE_NMS) ? n + 1 : PRE_NMS - 1];
            float4 n2 = bb[(n + 2 < PRE_NMS) ? n + 2 : PRE_NMS - 1];
            float4 n3 = bb[(n + 3 < PRE_NMS) ? n + 3 : PRE_NMS - 1];
            PROC(p0); if (K >= POST_NMS) done = true;
            if (!done) { PROC(p1); if (K >= POST_NMS) done = true; }
            if (!done) { PROC(p2); if (K >= POST_NMS) done = true; }
            if (!done) { PROC(p3); if (K >= POST_NMS) done = true; }
            p0 = n0; p1 = n1; p2 = n2; p3 = n3;
        }
    }

    // output kept[s*64+lane]
#pragma unroll
    for (int s = 0; s < 5; ++s) {
        int idx = s * 64 + lane;
        if (idx < POST_NMS) {
            float4 c;
            switch (s) {
            case 0: c = k0; break;
            case 1: c = k1; break;
            case 2: c = k2; break;
            case 3: c = k3; break;
            default: c = k4; break;
            }
            bool v = idx < K;
            float* o = out + (size_t)(b * POST_NMS + idx) * 5;
            o[0] = (float)b;
            o[1] = v ? c.x : 0.f;
            o[2] = v ? c.y : 0.f;
            o[3] = v ? c.z : 0.f;
            o[4] = v ? c.w : 0.f;
        }
    }
}

extern "C" void kernel_launch(void* const* d_in, const int* in_sizes, int n_in,
                              void* d_out, int out_size, void* d_ws, size_t ws_size,
                              hipStream_t stream) {
    const float* scores  = (const float*)d_in[0];
    const float* deltas  = (const float*)d_in[1];
    const float* im_info = (const float*)d_in[2];
    float* out = (float*)d_out;
    char* ws = (char*)d_ws;

    // layout: boxes(1.5MB) | scum(1MB) | gbase(4KB pad) | subhist(S MB) | masks
    const size_t boxB  = (size_t)B_NUM * PRE_NMS * 16;        // 1,536,000
    const size_t scumB = (size_t)B_NUM * NBINS * 4;           // 1,048,576
    const size_t fixedB = boxB + scumB + 4096;                // 2,588,672
    int NC = 0, S = 1;
    const int lad[2] = {2048, 1024};   // NC=2048: mask work/4 vs 4096; serial
                                       // fallback covers i* > NC exactly.
    for (int li = 0; li < 2 && !NC; ++li) {
        size_t mb = 2ull * lad[li] * lad[li];                 // 16*NW*NC*8 = 2*NC^2
        if (fixedB + 1048576ull + mb <= ws_size) {
            NC = lad[li];
            for (int ss = 8; ss >= 1; ss >>= 1)
                if (fixedB + (size_t)ss * 1048576ull + mb <= ws_size) { S = ss; break; }
        }
    }
    if (!NC) { NC = 1024; S = 1; }
    int NW = NC / 64;

    float4*   boxes   = (float4*)ws;
    uint32_t* scum    = (uint32_t*)(ws + boxB);
    uint32_t* gbase   = (uint32_t*)(ws + boxB + scumB);
    uint32_t* subhist = (uint32_t*)(ws + fixedB);
    uint64_t* masks   = (uint64_t*)(ws + fixedB + (size_t)S * 1048576ull);

    dim3 gh(S, B_NUM);
    k_hist<<<gh, 1024, 0, stream>>>(scores, subhist);
    k_scan<<<B_NUM, 1024, 0, stream>>>(subhist, S, scum, gbase);
    dim3 gg(6, B_NUM);
    k_group<<<gg, 1024, 0, stream>>>(scores, deltas, im_info, scum, gbase, boxes);
    int T = NW * (NW + 1) / 2;
    dim3 gm((T + 3) / 4, B_NUM);
    k_mask<<<gm, 256, 0, stream>>>(boxes, masks, NC, NW, T);
    k_resolve<<<B_NUM, 64, 0, stream>>>(boxes, masks, NC, NW, out);
}

// Round 10
// 161.975 us; speedup vs baseline: 4.3317x; 1.0537x over previous
//
#include <hip/hip_runtime.h>
#include <cstdint>
#include <cmath>

#define HWSZ    15000      // H*W = 100*150
#define W_FEAT  150
#define A_NUM   9
#define NPER    135000     // A_NUM * HWSZ
#define B_NUM   16
#define PRE_NMS 6000
#define POST_NMS 300
#define NBINS   16384      // top-14-bit histogram
#define GCAP    2048       // per-group sort capacity
#define NGRP    6          // ceil(6000/1024)

// 9 base anchors from generate_anchors(16,[0.5,1,2],[8,16,32]).
__device__ __constant__ float ANC[9][4] = {
    {-84.f,  -40.f,  99.f,  55.f},
    {-176.f, -88.f, 191.f, 103.f},
    {-360.f,-184.f, 375.f, 199.f},
    {-56.f,  -56.f,  71.f,  71.f},
    {-120.f,-120.f, 135.f, 135.f},
    {-248.f,-248.f, 263.f, 263.f},
    {-36.f,  -80.f,  51.f,  95.f},
    {-80.f, -168.f,  95.f, 183.f},
    {-168.f,-344.f, 183.f, 359.f}};

__device__ __forceinline__ uint32_t fkey(float s) {
    uint32_t u = __float_as_uint(s);
    return (u & 0x80000000u) ? ~u : (u | 0x80000000u);  // monotone key
}

// EXACT replacement for  __fdiv_rn(inter,den) > 0.7f  (see r6 derivation):
// m = midpoint(0.7f,next(0.7f)) = 0x1.666667p-1 (25 bits); m*(double)den exact.
__device__ __forceinline__ bool iou_gt(const float4& q, float qa,
                                       const float4& c, float ca) {
    float xx1 = fmaxf(q.x, c.x);
    float yy1 = fmaxf(q.y, c.y);
    float xx2 = fminf(q.z, c.z);
    float yy2 = fminf(q.w, c.w);
    float iw = fmaxf(0.0f, __fadd_rn(__fsub_rn(xx2, xx1), 1.0f));
    float ih = fmaxf(0.0f, __fadd_rn(__fsub_rn(yy2, yy1), 1.0f));
    float inter = __fmul_rn(iw, ih);
    float den = __fsub_rn(__fadd_rn(qa, ca), inter);
    return (double)inter >= 0x1.666667p-1 * (double)den;
}

__device__ __forceinline__ float area_of(const float4& c) {
    return __fmul_rn(__fadd_rn(__fsub_rn(c.z, c.x), 1.0f),
                     __fadd_rn(__fsub_rn(c.w, c.y), 1.0f));
}

// ---- K1: per-slice private histograms (no global atomics) -------------------
__global__ __launch_bounds__(1024) void k_hist(const float* __restrict__ scores,
                                               uint32_t* __restrict__ subhist) {
    __shared__ uint32_t hist[NBINS];          // 64KB
    int b = blockIdx.y, sx = blockIdx.x, S = gridDim.x, tid = threadIdx.x;
    for (int i = tid; i < NBINS; i += 1024) hist[i] = 0;
    __syncthreads();
    const float4* sc4 = (const float4*)(scores + (size_t)(b * 18 + 9) * HWSZ);
    int nf4 = NPER / 4;                       // 33750
    int per = (nf4 + S - 1) / S;
    int lo = sx * per, hi = min(lo + per, nf4);
    for (int i = lo + tid; i < hi; i += 1024) {
        float4 v = sc4[i];
        atomicAdd(&hist[fkey(v.x) >> 18], 1u);
        atomicAdd(&hist[fkey(v.y) >> 18], 1u);
        atomicAdd(&hist[fkey(v.z) >> 18], 1u);
        atomicAdd(&hist[fkey(v.w) >> 18], 1u);
    }
    __syncthreads();
    uint32_t* out = subhist + ((size_t)b * S + sx) * NBINS;
    for (int i = tid; i < NBINS; i += 1024) out[i] = hist[i];
}

// ---- K2: per-bin exclusive-from-top cum table + group base offsets ----------
__global__ __launch_bounds__(1024) void k_scan(const uint32_t* __restrict__ subhist,
                                               int S, uint32_t* __restrict__ scum,
                                               uint32_t* __restrict__ gbase) {
    __shared__ uint32_t tl[NBINS];            // 64KB summed hist
    __shared__ uint32_t psum[1024];
    __shared__ uint32_t gb[8];
    int b = blockIdx.x, tid = threadIdx.x;
    for (int i = tid; i < NBINS; i += 1024) {
        uint32_t t = 0;
        for (int u = 0; u < S; ++u) t += subhist[((size_t)b * S + u) * NBINS + i];
        tl[i] = t;
    }
    if (tid < 8) gb[tid] = 0xFFFFFFFFu;
    __syncthreads();
    int base = NBINS - 16 * (tid + 1);        // chunk tid: descending bins
    uint32_t csum = 0;
#pragma unroll
    for (int i = 0; i < 16; ++i) csum += tl[base + i];
    psum[tid] = csum;
    __syncthreads();
    for (int off = 1; off < 1024; off <<= 1) {
        uint32_t v = (tid >= off) ? psum[tid - off] : 0u;
        __syncthreads();
        psum[tid] += v;
        __syncthreads();
    }
    uint32_t c = tid ? psum[tid - 1] : 0u;    // exclusive cum before this chunk
    for (int i = 15; i >= 0; --i) {           // bins descending within chunk
        uint32_t t = tl[base + i];
        scum[(size_t)b * NBINS + base + i] = c;
        if (t && c < PRE_NMS) atomicMin(&gb[c >> 10], c);
        c += t;
    }
    __syncthreads();
    if (tid < 8) gbase[b * 8 + tid] = gb[tid];
}

// ---- K3: single-pass compact -> per-group global candidate buffers ----------
__global__ __launch_bounds__(1024) void k_compact(
        const float* __restrict__ scores, const uint32_t* __restrict__ scum,
        uint64_t* __restrict__ cand, uint32_t* __restrict__ gcnt) {
    __shared__ uint32_t sl[NBINS];            // 64KB scum cache
    __shared__ uint32_t lc[NGRP], lb[NGRP];
    int b = blockIdx.y, sx = blockIdx.x, S = gridDim.x, tid = threadIdx.x;
    for (int i = tid; i < NBINS; i += 1024) sl[i] = scum[(size_t)b * NBINS + i];
    if (tid < NGRP) lc[tid] = 0;
    __syncthreads();
    const float4* sc4 = (const float4*)(scores + (size_t)(b * 18 + 9) * HWSZ);
    int nf4 = NPER / 4;
    int per = (nf4 + S - 1) / S;
    int lo = sx * per, hi = min(lo + per, nf4);
    for (int i0 = lo; i0 < hi; i0 += 1024) {
        int i = i0 + tid;
        bool w[4];
        uint32_t gg[4], pp[4];
        uint64_t rec[4];
#pragma unroll
        for (int c = 0; c < 4; ++c) w[c] = false;
        if (i < hi) {
            float4 v = sc4[i];
            float cc[4] = {v.x, v.y, v.z, v.w};
#pragma unroll
            for (int c = 0; c < 4; ++c) {
                uint32_t k = fkey(cc[c]);
                uint32_t sc = sl[k >> 18];
                if (sc < PRE_NMS) {           // in top-6000 by bin
                    w[c] = true;
                    gg[c] = sc >> 10;         // rank group 0..5
                    pp[c] = atomicAdd(&lc[gg[c]], 1u);
                    int e = 4 * i + c;        // e = a*HWSZ + p
                    int a = e / HWSZ, p = e - a * HWSZ;
                    rec[c] = ((uint64_t)(~k) << 32) | (uint32_t)(p * A_NUM + a);
                }
            }
        }
        __syncthreads();
        if (tid < NGRP && lc[tid])            // one global atomic per group/chunk
            lb[tid] = atomicAdd(&gcnt[(b * NGRP + tid) * 16], lc[tid]);
        __syncthreads();
#pragma unroll
        for (int c = 0; c < 4; ++c)
            if (w[c]) {
                uint32_t pos = lb[gg[c]] + pp[c];
                if (pos < GCAP)
                    cand[((size_t)b * NGRP + gg[c]) * GCAP + pos] = rec[c];
            }
        __syncthreads();
        if (tid < NGRP) lc[tid] = 0;
        __syncthreads();
    }
}

// ---- K4: per-group bitonic(2048) + decode (no score re-read) ----------------
__global__ __launch_bounds__(1024) void k_group(
        const uint64_t* __restrict__ cand, const uint32_t* __restrict__ gcnt,
        const float* __restrict__ deltas, const float* __restrict__ im_info,
        const uint32_t* __restrict__ gbase, float4* __restrict__ boxes) {
    __shared__ uint64_t s[GCAP];              // 16KB sort buffer
    int b = blockIdx.y, g = blockIdx.x, tid = threadIdx.x;
    uint32_t base = gbase[b * 8 + g];
    if (base == 0xFFFFFFFFu) return;          // empty group
    uint32_t cnt = min(gcnt[(b * NGRP + g) * 16], (uint32_t)GCAP);
    for (int i = tid; i < GCAP; i += 1024)
        s[i] = (i < (int)cnt) ? cand[((size_t)b * NGRP + g) * GCAP + i] : ~0ull;
    __syncthreads();
    // bitonic sort 2048 (1024 threads = 1 pair each)
    for (unsigned k = 2; k <= GCAP; k <<= 1) {
        for (unsigned j = k >> 1; j; j >>= 1) {
            unsigned p = tid;
            unsigned i = ((p & ~(j - 1)) << 1) | (p & (j - 1));
            unsigned ixj = i | j;
            uint64_t x = s[i], y = s[ixj];
            bool up = ((i & k) == 0);
            if (up ? (x > y) : (x < y)) { s[i] = y; s[ixj] = x; }
            __syncthreads();
        }
    }
    // decode ranks [base, base+cnt) ∩ [0, PRE_NMS)
    float him = im_info[b * 3 + 0], wim = im_info[b * 3 + 1];
    float ymax = __fsub_rn(him, 1.0f), xmax = __fsub_rn(wim, 1.0f);
    for (int r = tid; r < GCAP; r += 1024) {
        uint32_t P = base + (uint32_t)r;
        uint32_t idx = (uint32_t)s[r];
        if (r < (int)cnt && P < PRE_NMS && idx < NPER) {
            int a = idx % A_NUM;
            int p = idx / A_NUM;
            int wc = p % W_FEAT, hr = p / W_FEAT;
            float ax1 = ANC[a][0] + (float)(wc * 16);
            float ay1 = ANC[a][1] + (float)(hr * 16);
            float ax2 = ANC[a][2] + (float)(wc * 16);
            float ay2 = ANC[a][3] + (float)(hr * 16);
            const float* dp = deltas + (size_t)(b * 36 + a * 4) * HWSZ + p;
            float dx = dp[0], dy = dp[HWSZ], dw = dp[2 * HWSZ], dh = dp[3 * HWSZ];
            float ww = __fadd_rn(__fsub_rn(ax2, ax1), 1.0f);
            float hh = __fadd_rn(__fsub_rn(ay2, ay1), 1.0f);
            float cx = __fadd_rn(ax1, __fmul_rn(0.5f, ww));
            float cy = __fadd_rn(ay1, __fmul_rn(0.5f, hh));
            float pcx = __fadd_rn(__fmul_rn(dx, ww), cx);
            float pcy = __fadd_rn(__fmul_rn(dy, hh), cy);
            float ew = (float)exp((double)dw);
            float eh = (float)exp((double)dh);
            float pw = __fmul_rn(ew, ww);
            float ph = __fmul_rn(eh, hh);
            float x1 = __fsub_rn(pcx, __fmul_rn(0.5f, pw));
            float y1 = __fsub_rn(pcy, __fmul_rn(0.5f, ph));
            float x2 = __fadd_rn(pcx, __fmul_rn(0.5f, pw));
            float y2 = __fadd_rn(pcy, __fmul_rn(0.5f, ph));
            float4 bx;
            bx.x = fminf(fmaxf(x1, 0.0f), xmax);
            bx.y = fminf(fmaxf(y1, 0.0f), ymax);
            bx.z = fminf(fmaxf(x2, 0.0f), xmax);
            bx.w = fminf(fmaxf(y2, 0.0f), ymax);
            boxes[(size_t)b * PRE_NMS + P] = bx;
        }
    }
}

// ---- K5: suppression bitmask for first NC candidates (64x64 wave tiles) -----
__global__ __launch_bounds__(256) void k_mask(const float4* __restrict__ boxes,
                                              uint64_t* __restrict__ masks,
                                              int NC, int NW, int T) {
    int b = blockIdx.y;
    int wv = threadIdx.x >> 6, lane = threadIdx.x & 63;
    int t = blockIdx.x * 4 + wv;
    if (t >= T) return;
    int ti = 0, rem = t;
    while (rem >= NW - ti) { rem -= NW - ti; ++ti; }   // upper-triangle map
    int tj = ti + rem;
    __shared__ float4 colb[4][64];
    __shared__ float  cola[4][64];
    const float4* bb = boxes + (size_t)b * PRE_NMS;
    int i = ti * 64 + lane;
    float4 c = bb[i];
    float ca = area_of(c);
    float4 q0 = bb[tj * 64 + lane];
    colb[wv][lane] = q0;
    cola[wv][lane] = area_of(q0);
    asm volatile("s_waitcnt lgkmcnt(0)" ::: "memory");  // single-wave LDS sync
    __builtin_amdgcn_wave_barrier();
    uint64_t m = 0;
    if (ti == tj) {
#pragma unroll
        for (int jj = 0; jj < 64; ++jj) {
            bool hit = (jj > lane) && iou_gt(colb[wv][jj], cola[wv][jj], c, ca);
            m |= ((uint64_t)(hit ? 1u : 0u)) << jj;
        }
    } else {
#pragma unroll
        for (int jj = 0; jj < 64; ++jj) {
            bool hit = iou_gt(colb[wv][jj], cola[wv][jj], c, ca);
            m |= ((uint64_t)(hit ? 1u : 0u)) << jj;
        }
    }
    masks[((size_t)b * NW + tj) * NC + i] = m;
}

// kept-list register helpers (slot s holds kept[s*64+lane])
#define PROC(P)                                                                \
    do {                                                                       \
        float ca = area_of(P);                                                 \
        bool viol = false;                                                     \
        if (K > 0)   viol |= (lane       < K) & iou_gt(k0, a0, P, ca);         \
        if (K > 64)  viol |= (lane + 64  < K) & iou_gt(k1, a1, P, ca);         \
        if (K > 128) viol |= (lane + 128 < K) & iou_gt(k2, a2, P, ca);         \
        if (K > 192) viol |= (lane + 192 < K) & iou_gt(k3, a3, P, ca);         \
        if (K > 256) viol |= (lane + 256 < K) & iou_gt(k4, a4, P, ca);         \
        if (!__any((int)viol)) {                                               \
            int sl = K >> 6, tg = K & 63;                                      \
            if (lane == tg) {                                                  \
                switch (sl) {                                                  \
                case 0: k0 = P; a0 = ca; break;                                \
                case 1: k1 = P; a1 = ca; break;                                \
                case 2: k2 = P; a2 = ca; break;                                \
                case 3: k3 = P; a3 = ca; break;                                \
                default: k4 = P; a4 = ca; break;                               \
                }                                                              \
            }                                                                  \
            ++K;                                                               \
        }                                                                      \
    } while (0)

// one mask-walk step: consume ring reg RG (= row i), reload with row i+8
#define RSTEP(RG)                                                              \
    do {                                                                       \
        if (!fin && i < NC) {                                                  \
            bool mine = (lane == (i >> 6));                                    \
            bool sb = mine && ((sup >> (i & 63)) & 1ull);                      \
            if (!__any((int)sb)) {                                             \
                int sl = K >> 6, tg = K & 63;                                  \
                if (lane == tg) {                                              \
                    switch (sl) {                                              \
                    case 0: i0 = i; break;                                     \
                    case 1: i1 = i; break;                                     \
                    case 2: i2 = i; break;                                     \
                    case 3: i3 = i; break;                                     \
                    default: i4 = i; break;                                    \
                    }                                                          \
                }                                                              \
                if (lane < NW) sup |= RG;                                      \
                ++K;                                                           \
                if (K >= POST_NMS) fin = true;                                 \
            }                                                                  \
            int nx = i + 8; if (nx >= NC) nx = NC - 1;                         \
            RG = mrow[nx];                                                     \
            ++i;                                                               \
        }                                                                      \
    } while (0)

// ---- K6: greedy resolve, one wave per batch ---------------------------------
__global__ __launch_bounds__(64) void k_resolve(const float4* __restrict__ boxes,
                                                const uint64_t* __restrict__ masks,
                                                int NC, int NW,
                                                float* __restrict__ out) {
    int b = blockIdx.x, lane = threadIdx.x;
    const float4* bb = boxes + (size_t)b * PRE_NMS;
    int K = 0;
    int i0 = 0, i1 = 0, i2 = 0, i3 = 0, i4 = 0;
    bool fin = false;

    if (NC > 0) {
        const uint64_t* mrow =
            masks + ((size_t)b * NW + (lane < NW ? lane : NW - 1)) * NC;
        uint64_t sup = 0;
        uint64_t r0 = mrow[0], r1 = mrow[1], r2 = mrow[2], r3 = mrow[3];
        uint64_t r4 = mrow[4], r5 = mrow[5], r6 = mrow[6], r7 = mrow[7];
        int i = 0;
        while (i < NC && !fin) {
            RSTEP(r0); RSTEP(r1); RSTEP(r2); RSTEP(r3);
            RSTEP(r4); RSTEP(r5); RSTEP(r6); RSTEP(r7);
        }
    }

    // gather kept boxes into lane-cycled registers
    float4 k0, k1, k2, k3, k4;
    float a0, a1, a2, a3, a4;
    { int id = (lane       < K) ? i0 : 0; k0 = bb[id]; a0 = area_of(k0); }
    { int id = (lane + 64  < K) ? i1 : 0; k1 = bb[id]; a1 = area_of(k1); }
    { int id = (lane + 128 < K) ? i2 : 0; k2 = bb[id]; a2 = area_of(k2); }
    { int id = (lane + 192 < K) ? i3 : 0; k3 = bb[id]; a3 = area_of(k3); }
    { int id = (lane + 256 < K) ? i4 : 0; k4 = bb[id]; a4 = area_of(k4); }

    // fallback: continue exact greedy walk past NC if needed
    if (!fin && NC < PRE_NMS) {
        float4 p0 = bb[NC + 0], p1 = bb[NC + 1], p2 = bb[NC + 2], p3 = bb[NC + 3];
        bool done = false;
        for (int r = NC; r < PRE_NMS && !done; r += 4) {
            int n = r + 4;
            float4 n0 = bb[(n + 0 < PRE_NMS) ? n + 0 : PRE_NMS - 1];
            float4 n1 = bb[(n + 1 < PRE_NMS) ? n + 1 : PRE_NMS - 1];
            float4 n2 = bb[(n + 2 < PRE_NMS) ? n + 2 : PRE_NMS - 1];
            float4 n3 = bb[(n + 3 < PRE_NMS) ? n + 3 : PRE_NMS - 1];
            PROC(p0); if (K >= POST_NMS) done = true;
            if (!done) { PROC(p1); if (K >= POST_NMS) done = true; }
            if (!done) { PROC(p2); if (K >= POST_NMS) done = true; }
            if (!done) { PROC(p3); if (K >= POST_NMS) done = true; }
            p0 = n0; p1 = n1; p2 = n2; p3 = n3;
        }
    }

    // output kept[s*64+lane]
#pragma unroll
    for (int s = 0; s < 5; ++s) {
        int idx = s * 64 + lane;
        if (idx < POST_NMS) {
            float4 c;
            switch (s) {
            case 0: c = k0; break;
            case 1: c = k1; break;
            case 2: c = k2; break;
            case 3: c = k3; break;
            default: c = k4; break;
            }
            bool v = idx < K;
            float* o = out + (size_t)(b * POST_NMS + idx) * 5;
            o[0] = (float)b;
            o[1] = v ? c.x : 0.f;
            o[2] = v ? c.y : 0.f;
            o[3] = v ? c.z : 0.f;
            o[4] = v ? c.w : 0.f;
        }
    }
}

extern "C" void kernel_launch(void* const* d_in, const int* in_sizes, int n_in,
                              void* d_out, int out_size, void* d_ws, size_t ws_size,
                              hipStream_t stream) {
    const float* scores  = (const float*)d_in[0];
    const float* deltas  = (const float*)d_in[1];
    const float* im_info = (const float*)d_in[2];
    float* out = (float*)d_out;
    char* ws = (char*)d_ws;

    // layout: boxes | scum | gbase+gcnt(8KB) | subhist(S MB) | cand | masks
    const size_t boxB   = (size_t)B_NUM * PRE_NMS * 16;       // 1,536,000
    const size_t scumB  = (size_t)B_NUM * NBINS * 4;          // 1,048,576
    const size_t metaB  = 8192;                               // gbase 512B + gcnt 6KB
    const size_t candB  = (size_t)B_NUM * NGRP * GCAP * 8;    // 1,572,864
    const size_t fixedB = boxB + scumB + metaB;
    int NC = 0, S = 1;
    const int lad[2] = {2048, 1024};
    for (int li = 0; li < 2 && !NC; ++li) {
        size_t mb = 2ull * lad[li] * lad[li];                 // 16*NW*NC*8 = 2*NC^2
        if (fixedB + 1048576ull + candB + mb <= ws_size) {
            NC = lad[li];
            for (int ss = 8; ss >= 1; ss >>= 1)
                if (fixedB + (size_t)ss * 1048576ull + candB + mb <= ws_size) { S = ss; break; }
        }
    }
    if (!NC) { NC = 1024; S = 1; }
    int NW = NC / 64;

    float4*   boxes   = (float4*)ws;
    uint32_t* scum    = (uint32_t*)(ws + boxB);
    uint32_t* gbase   = (uint32_t*)(ws + boxB + scumB);
    uint32_t* gcnt    = (uint32_t*)(ws + boxB + scumB + 1024);
    uint32_t* subhist = (uint32_t*)(ws + fixedB);
    uint64_t* cand    = (uint64_t*)(ws + fixedB + (size_t)S * 1048576ull);
    uint64_t* masks   = (uint64_t*)(ws + fixedB + (size_t)S * 1048576ull + candB);

    hipMemsetAsync(gcnt, 0, (size_t)B_NUM * NGRP * 16 * 4, stream);

    dim3 gh(S, B_NUM);
    k_hist<<<gh, 1024, 0, stream>>>(scores, subhist);
    k_scan<<<B_NUM, 1024, 0, stream>>>(subhist, S, scum, gbase);
    k_compact<<<gh, 1024, 0, stream>>>(scores, scum, cand, gcnt);
    dim3 gg(NGRP, B_NUM);
    k_group<<<gg, 1024, 0, stream>>>(cand, gcnt, deltas, im_info, gbase, boxes);
    int T = NW * (NW + 1) / 2;
    dim3 gm((T + 3) / 4, B_NUM);
    k_mask<<<gm, 256, 0, stream>>>(boxes, masks, NC, NW, T);
    k_resolve<<<B_NUM, 64, 0, stream>>>(boxes, masks, NC, NW, out);
}